// Round 5
// baseline (343.638 us; speedup 1.0000x reference)
//
#include <hip/hip_runtime.h>
#include <hip/hip_bf16.h>

// ---------------------------------------------------------------------------
// OptimizedAttention R8: fused QKV proj -> K-RoPE -> causal GQA flash attn
// -> output proj.
// R8: attn re-gridded for wave parallelism. R7 diagnosis: 512 blocks x 4
// waves = 2 waves/SIMD -> latency-bound (MfmaUtil 19%, VALUBusy 46%,
// occupancy 19%); uniform work alone didn't help. New: 1024 blocks x 4
// waves, 16 queries/wave, uniform via 64-query tile pairs (p,31-p) = 33
// steps/block. LDS 40960 B = exactly 4 blocks/CU -> 16 waves/CU (4/SIMD),
// all resident, no tail. Every wave computes every step (16q span never
// exceeds key frontier); exactly one diagonal step per wave per pass.
// GEMMs: 256^2 8-phase schedule (R6, verified): T2 chunk-XOR swizzle +
// T3/T4 counted-vmcnt prefetch + T5 setprio; ledger in gemm_bt8 comment.
// B=2 S=2048 H=2048 NH=32 NKV=8 DH=64 N_REP=4 THETA=1e4
// ---------------------------------------------------------------------------

using bf16 = __hip_bfloat16;
typedef __attribute__((ext_vector_type(8))) __bf16 bf8v;   // MFMA A/B frag (4 VGPR)
typedef __attribute__((ext_vector_type(4))) float  f4v;    // MFMA C/D frag

#define AS1 __attribute__((address_space(1)))
#define AS3 __attribute__((address_space(3)))

constexpr int cB = 2, cS = 2048, cH = 2048, cNH = 32, cNKV = 8, cDH = 64;
constexpr int cQKVW = 3072;   // fused QKV row width (2048 Q + 512 K + 512 V)

template <int N> struct ic { static constexpr int value = N; };

__device__ __forceinline__ void async_cp16(const bf16* g, bf16* l) {
    __builtin_amdgcn_global_load_lds((const AS1 unsigned int*)(const void*)g,
                                     (AS3 unsigned int*)(void*)l, 16, 0, 0);
}

__device__ __forceinline__ f4v mfma_16x16x32(bf8v a, bf8v b, f4v c) {
    return __builtin_amdgcn_mfma_f32_16x16x32_bf16(a, b, c, 0, 0, 0);
}

__device__ __forceinline__ void store_out(float* p, float v) { *p = v; }
__device__ __forceinline__ void store_out(bf16*  p, float v) { *p = __float2bfloat16(v); }

// ---------------------------------------------------------------------------
__global__ void cvt_f32_bf16(const float* __restrict__ in, bf16* __restrict__ outp, int n4) {
    int i = blockIdx.x * 256 + threadIdx.x;
    if (i >= n4) return;
    float4 v = ((const float4*)in)[i];
    union { bf16 h[4]; uint2 u; } p;
    p.h[0] = __float2bfloat16(v.x);
    p.h[1] = __float2bfloat16(v.y);
    p.h[2] = __float2bfloat16(v.z);
    p.h[3] = __float2bfloat16(v.w);
    ((uint2*)outp)[i] = p.u;
}

// fp32 [R][C] -> bf16 [C][R] transpose-convert (weights -> B^T layout)
__global__ void transpose_f32_bf16(const float* __restrict__ in, bf16* __restrict__ outp,
                                   int R, int C) {
    __shared__ float tile[32][33];
    int c0 = blockIdx.x * 32, r0 = blockIdx.y * 32;
    int tx = threadIdx.x, ty = threadIdx.y;
    for (int i = ty; i < 32; i += 8)
        tile[i][tx] = in[(long)(r0 + i) * C + c0 + tx];
    __syncthreads();
    for (int i = ty; i < 32; i += 8)
        outp[(long)(c0 + i) * R + r0 + tx] = __float2bfloat16(tile[tx][i]);
}

// V slice of QKV [tok][3072] (cols 2560..3071) -> VT [B][NKV][DH][S]
__global__ void transpose_v(const bf16* __restrict__ Vsrc, bf16* __restrict__ VT) {
    __shared__ float tile[32][33];
    int z = blockIdx.z;               // b*NKV + kv
    int b = z >> 3, kv = z & 7;
    int d0 = blockIdx.x * 32, s0 = blockIdx.y * 32;
    int tx = threadIdx.x, ty = threadIdx.y;
    for (int i = ty; i < 32; i += 8)
        tile[i][tx] = __bfloat162float(Vsrc[(long)(b * cS + s0 + i) * cQKVW + kv * cDH + d0 + tx]);
    __syncthreads();
    for (int i = ty; i < 32; i += 8)
        VT[((long)(b * cNKV + kv) * cDH + d0 + i) * cS + s0 + tx] = __float2bfloat16(tile[tx][i]);
}

// In-place RoPE on bf16 rows of stride `rowstride`; pair (d, d+32), d<32.
__global__ void rope_kernel(bf16* __restrict__ X, const int* __restrict__ pos,
                            int nh, int hshift, int rowstride, int total) {
    int idx = blockIdx.x * 256 + threadIdx.x;
    if (idx >= total) return;
    int d   = idx & 31;
    int t2  = idx >> 5;
    int hh  = t2 & (nh - 1);
    int tok = t2 >> hshift;
    float p   = (float)pos[tok];
    float inv = __expf(-(float)(2 * d) * (1.0f / 64.0f) * 9.210340371976184f);
    float ang = p * inv;
    float s = sinf(ang), c = cosf(ang);
    long base = (long)tok * rowstride + hh * 64 + d;
    float x1 = __bfloat162float(X[base]);
    float x2 = __bfloat162float(X[base + 32]);
    X[base]      = __float2bfloat16(x1 * c - x2 * s);
    X[base + 32] = __float2bfloat16(x2 * c + x1 * s);
}

// ---------------------------------------------------------------------------
// bf16 GEMM, B-transposed, 256x256 tile, 8-phase deep-pipelined schedule.
// C[M][N] = A[M][K] * BT[N][K]^T.  M%256==0, N%256==0, K%64==0, K/64 >= 3.
// 512 threads = 8 waves (2M x 4N), wave tile 128x64, acc[8][4].
// LDS: 2 bufs x (A[256][64] + B[256][64]) bf16 = 128 KiB.
// Chunk-XOR swizzle: 16B chunk c of row r stored at slot c^(r&7); applied
// to the global SOURCE address (global_load_lds writes linearly) and to
// the ds_read address -- frag reads are 2 lanes/bank (conflict-free).
// Per K-tile (4 phases of {ds_read; prefetch-issue; barrier; lgkmcnt(0);
// setprio(1); 16 MFMA; setprio(0); [counted vmcnt]; barrier}):
//   ph0: issue A-u0(t+1)->buf^1   ph1: issue A-u1(t+1)->buf^1, vmcnt(8)
//   ph2: issue B-h0(t+2)->buf     ph3: issue B-h1(t+2)->buf,   vmcnt(6)
// B region of buf is dead after ph0 (read into regs, 2 barriers earlier),
// so B(t+2) staging into the live buffer is race-free. In-flight ledger
// at tile entry: {A-u1(t)[2], B(t+1)[4]} = 6 loads; waits keep the tile
// being read always fully landed, never draining to 0 mid-loop.
// ---------------------------------------------------------------------------
template <typename OutT>
__global__ __launch_bounds__(512)
void gemm_bt8(const bf16* __restrict__ A, const bf16* __restrict__ BT,
              OutT* __restrict__ C, int M, int N, int K) {
    __shared__ __align__(16) bf16 Al[2][256 * 64];   // 32 KB x2
    __shared__ __align__(16) bf16 Bl[2][256 * 64];   // 32 KB x2
    const int tid  = threadIdx.x;
    const int lane = tid & 63;
    const int wave = tid >> 6;
    const int wm = wave >> 2, wn = wave & 3;         // 2M x 4N wave grid
    const int lm = lane & 15, lq = lane >> 4;
    const int bm = blockIdx.x * 256, bn = blockIdx.y * 256;
    const int NT = K >> 6;                           // K-tiles of 64

    f4v acc[8][4];
    #pragma unroll
    for (int i = 0; i < 8; ++i)
        #pragma unroll
        for (int j = 0; j < 4; ++j)
            for (int r = 0; r < 4; ++r) acc[i][j][r] = 0.f;

    // ---- staging addressing -------------------------------------------------
    const bf16* aP[2][2]; const bf16* bP[2][2];
    int aD[2][2], bD[2][2];
    #pragma unroll
    for (int u = 0; u < 2; ++u)
        #pragma unroll
        for (int i = 0; i < 2; ++i) {
            int g = tid + i * 512;
            int ur = g >> 3, dc = g & 7;
            int row = ur + (ur & 64) + u * 64;
            int gch = dc ^ (row & 7);
            aP[u][i] = A + (long)(bm + row) * K + gch * 8;
            aD[u][i] = row * 64 + dc * 8;
        }
    #pragma unroll
    for (int h = 0; h < 2; ++h)
        #pragma unroll
        for (int i = 0; i < 2; ++i) {
            int g = tid + i * 512;
            int ur = g >> 3, dc = g & 7;
            int row = h * 128 + ur;
            int gch = dc ^ (row & 7);
            bP[h][i] = BT + (long)(bn + row) * K + gch * 8;
            bD[h][i] = row * 64 + dc * 8;
        }

    auto stageA = [&](int buf, int t, int u) {
        long ko = (long)t * 64;
        async_cp16(aP[u][0] + ko, &Al[buf][aD[u][0]]);
        async_cp16(aP[u][1] + ko, &Al[buf][aD[u][1]]);
    };
    auto stageB = [&](int buf, int t, int h) {
        long ko = (long)t * 64;
        async_cp16(bP[h][0] + ko, &Bl[buf][bD[h][0]]);
        async_cp16(bP[h][1] + ko, &Bl[buf][bD[h][1]]);
    };

    // ---- fragment read addressing (row&7 == lm&7 for all frag rows) --------
    const int x7 = lm & 7;
    const int co0 = (lq ^ x7) * 8;           // k-half 0: chunk lq
    const int co1 = ((4 + lq) ^ x7) * 8;     // k-half 1: chunk 4+lq
    const int abase = (wm * 128 + lm) * 64;
    const int bbase = (wn * 64 + lm) * 64;

    // ---- prologue: B(0), A-u0(0), A-u1(0), B(1); first 6 loads must land ---
    stageB(0, 0, 0); stageB(0, 0, 1); stageA(0, 0, 0); stageA(0, 0, 1);
    stageB(1, 1, 0); stageB(1, 1, 1);
    asm volatile("s_waitcnt vmcnt(6)" ::: "memory");  // B(0)+A-u0(0) landed
    asm volatile("s_barrier" ::: "memory");

    auto ktile = [&](int t, bool ia, bool ib, auto w1, auto w3) {
        const int cb = t & 1;
        const bf16* Ac = &Al[cb][0];
        const bf16* Bc = &Bl[cb][0];
        bf8v bfr[4][2];
        #pragma unroll
        for (int q = 0; q < 4; ++q) {
            bf8v afr[2][2];
            if (q == 0) {
                #pragma unroll
                for (int n = 0; n < 4; ++n) {
                    bfr[n][0] = *(const bf8v*)&Bc[bbase + n * 1024 + co0];
                    bfr[n][1] = *(const bf8v*)&Bc[bbase + n * 1024 + co1];
                }
            }
            #pragma unroll
            for (int i2 = 0; i2 < 2; ++i2) {
                afr[i2][0] = *(const bf8v*)&Ac[abase + (q * 2 + i2) * 1024 + co0];
                afr[i2][1] = *(const bf8v*)&Ac[abase + (q * 2 + i2) * 1024 + co1];
            }
            if (q == 0 && ia) stageA(cb ^ 1, t + 1, 0);
            if (q == 1 && ia) stageA(cb ^ 1, t + 1, 1);
            if (q == 2 && ib) stageB(cb, t + 2, 0);
            if (q == 3 && ib) stageB(cb, t + 2, 1);
            asm volatile("s_barrier" ::: "memory");
            asm volatile("s_waitcnt lgkmcnt(0)" ::: "memory");
            __builtin_amdgcn_s_setprio(1);
            #pragma unroll
            for (int i2 = 0; i2 < 2; ++i2)
                #pragma unroll
                for (int n = 0; n < 4; ++n) {
                    acc[q * 2 + i2][n] = mfma_16x16x32(afr[i2][0], bfr[n][0], acc[q * 2 + i2][n]);
                    acc[q * 2 + i2][n] = mfma_16x16x32(afr[i2][1], bfr[n][1], acc[q * 2 + i2][n]);
                }
            __builtin_amdgcn_s_setprio(0);
            if (q == 1) {
                if constexpr (decltype(w1)::value == 8)
                    asm volatile("s_waitcnt vmcnt(8)" ::: "memory");  // A-u1(t) landed
                else
                    asm volatile("s_waitcnt vmcnt(0)" ::: "memory");  // last tile drain
            }
            if (q == 3) {
                if constexpr (decltype(w3)::value == 1)
                    asm volatile("s_waitcnt vmcnt(6)" ::: "memory");  // B(t+1)+A-u0(t+1) landed
                else if constexpr (decltype(w3)::value == 2)
                    asm volatile("s_waitcnt vmcnt(2)" ::: "memory");  // peeled NT-2 boundary
            }
            asm volatile("s_barrier" ::: "memory");
        }
    };

    int t = 0;
    for (; t + 2 < NT; ++t) ktile(t, true, true, ic<8>{}, ic<1>{});
    ktile(t, true, false, ic<8>{}, ic<2>{});   // t = NT-2: no B(NT) issues
    ++t;
    ktile(t, false, false, ic<0>{}, ic<0>{});  // t = NT-1: drain A-u1 at ph1

    // ---- epilogue ----------------------------------------------------------
    #pragma unroll
    for (int mi = 0; mi < 8; ++mi) {
        int row = bm + wm * 128 + mi * 16 + lq * 4;
        #pragma unroll
        for (int n = 0; n < 4; ++n) {
            int col = bn + wn * 64 + n * 16 + lm;
            for (int r = 0; r < 4; ++r)
                store_out(&C[(long)(row + r) * N + col], acc[mi][n][r]);
        }
    }
}

// ---------------------------------------------------------------------------
// Causal GQA flash attention. 1024 blocks; block = (pair p, rep, b, kvh),
// 4 waves x 16 queries. Two sequential 64-query passes: q-tiles (31-p)
// then p -> exactly 33 key-steps per block (uniform). LDS 40960 B =
// exactly 4 blocks/CU -> 16 waves/CU (4 waves/SIMD), all 1024 blocks
// resident, no tail. Every wave computes every step of its pass; one
// diagonal (masked) step per wave per pass. Per 64-key step: K/VT tiles
// async-staged to LDS (XOR-swizzled source chunks), double-buffered,
// raw s_barrier + vmcnt(4). Fixed-base exp2 softmax (scale/ln2 folded
// into Q); Q-RoPE fused; setprio around MFMA. XCD affinity: idx&7 = kvh.
// ---------------------------------------------------------------------------
__global__ __launch_bounds__(256)
void attn_kernel(const bf16* __restrict__ QKV, const bf16* __restrict__ VT,
                 const int* __restrict__ pos, bf16* __restrict__ O) {
    __shared__ __align__(16) bf16 Kl[2][64 * 64];   // [buf][key][dh]   8KB x2
    __shared__ __align__(16) bf16 Vl[2][64 * 64];   // [buf][d][key]    8KB x2
    __shared__ __align__(16) bf16 Pl[4][16 * 64];   // per-wave P tile  2KB x4
    const int tid  = threadIdx.x;
    const int wave = tid >> 6, lane = tid & 63;
    const int lm = lane & 15, lq = lane >> 4;
    // block swizzle: idx = pair*64 + rep*16 + (b*8 + kvh)
    const int idx = blockIdx.x;
    const int pair = idx >> 6;                      // 0..15
    const int bh2 = idx & 15;
    const int rep = (idx >> 4) & 3;
    const int b = bh2 >> 3, kvh = bh2 & 7;
    const int h = kvh * 4 + rep;

    constexpr float SCALE = 0.18033688011112042f;

    // ---- pass-independent addressing ----
    bf16* pw = &Pl[wave][0];
    const int x7 = lm & 7;
    int wr_addr[4], rd_addr[2];
    for (int t = 0; t < 4; ++t)
        wr_addr[t] = lm * 64 + (((t * 2 + (lq >> 1)) ^ x7) * 8) + (lq & 1) * 4;
    for (int c = 0; c < 2; ++c)
        rd_addr[c] = lm * 64 + (((c * 4 + lq) ^ x7) * 8);

    const int srow = tid >> 3, sch = tid & 7;
    const bf16* kgb = QKV + (long)b * cS * cQKVW + 2048 + kvh * cDH;
    const bf16* vgb = VT + (long)(b * cNKV + kvh) * cDH * cS;
    const int sc8 = (sch ^ (srow & 7)) * 8;    // (32+srow)&7 == srow&7
    const bf16* kp0 = kgb + (long)srow * cQKVW + sc8;
    const bf16* kp1 = kgb + (long)(32 + srow) * cQKVW + sc8;
    const bf16* vp0 = vgb + (long)srow * cS + sc8;
    const bf16* vp1 = vgb + (long)(32 + srow) * cS + sc8;
    auto stage = [&](int buf, int j0) {
        long ko = (long)j0 * cQKVW;
        async_cp16(kp0 + ko, &Kl[buf][tid * 8]);
        async_cp16(kp1 + ko, &Kl[buf][2048 + tid * 8]);
        async_cp16(vp0 + j0, &Vl[buf][tid * 8]);
        async_cp16(vp1 + j0, &Vl[buf][2048 + tid * 8]);
    };

    for (int pass = 0; pass < 2; ++pass) {
        const int qblk = pass ? pair : 31 - pair;   // 64-query tile; heavy first
        const int q0 = qblk * 64;
        const int qw = q0 + wave * 16;              // this wave's 16 queries
        const int qi = qw + lm;                     // this lane's query
        const int nsteps = qblk + 1;

        // ---- Q fragment (B-frag: n=q=lm, k=dh=lq*8+j), RoPE + scale fused
        bf8v qf[2];
        {
            const bf16* qrow = QKV + (long)(b * cS + qi) * cQKVW + h * cDH;
            float p = (float)pos[b * cS + qi];
            bf8v r0 = *(const bf8v*)(qrow + lq * 8);
            bf8v r1 = *(const bf8v*)(qrow + 32 + lq * 8);
            bf8v t0, t1;
            for (int j = 0; j < 8; ++j) {
                int d = lq * 8 + j;
                float inv = __expf(-(float)(2 * d) * (1.0f / 64.0f) * 9.210340371976184f);
                float sn, cs;
                __sincosf(p * inv, &sn, &cs);
                float a = (float)r0[j], c2 = (float)r1[j];
                t0[j] = (__bf16)((a * cs - c2 * sn) * SCALE);
                t1[j] = (__bf16)((c2 * cs + a * sn) * SCALE);
            }
            qf[0] = t0; qf[1] = t1;
        }

        float lrow = 0.f;
        f4v o[4];
        for (int t = 0; t < 4; ++t)
            for (int r = 0; r < 4; ++r) o[t][r] = 0.f;

        stage(0, 0);
        for (int step = 0; step < nsteps; ++step) {
            const int j0 = step * 64;
            const int cur = step & 1;
            if (step + 1 < nsteps) {
                stage(cur ^ 1, j0 + 64);
                asm volatile("s_waitcnt vmcnt(4)" ::: "memory");  // current tile only
            } else {
                asm volatile("s_waitcnt vmcnt(0)" ::: "memory");
            }
            asm volatile("s_barrier" ::: "memory");

            // ---- S^T = K . Q^T : A-frag = K[key][dh] from LDS ----
            f4v st[4];
            for (int t = 0; t < 4; ++t)
                for (int r = 0; r < 4; ++r) st[t][r] = 0.f;
            __builtin_amdgcn_s_setprio(1);
            for (int t = 0; t < 4; ++t) {
                int kr = t * 16 + lm;
                bf8v kf0 = *(const bf8v*)&Kl[cur][kr * 64 + ((lq ^ (kr & 7)) * 8)];
                bf8v kf1 = *(const bf8v*)&Kl[cur][kr * 64 + (((4 + lq) ^ (kr & 7)) * 8)];
                st[t] = mfma_16x16x32(kf0, qf[0], st[t]);
                st[t] = mfma_16x16x32(kf1, qf[1], st[t]);
            }
            __builtin_amdgcn_s_setprio(0);
            // ---- V^T frags (A-frag: m=d, k=key) ----
            bf8v vf[4][2];
            for (int t = 0; t < 4; ++t) {
                int vr = t * 16 + lm;
                vf[t][0] = *(const bf8v*)&Vl[cur][vr * 64 + ((lq ^ (vr & 7)) * 8)];
                vf[t][1] = *(const bf8v*)&Vl[cur][vr * 64 + (((4 + lq) ^ (vr & 7)) * 8)];
            }
            // ---- fixed-base softmax (bare v_exp_f32) ----
            const bool full = (j0 + 63 <= qw);
            float part = 0.f;
            if (full) {
                for (int t = 0; t < 4; ++t)
                    for (int r = 0; r < 4; ++r) {
                        float pv = __builtin_amdgcn_exp2f(st[t][r]);
                        st[t][r] = pv;
                        part += pv;
                    }
            } else {
                for (int t = 0; t < 4; ++t)
                    for (int r = 0; r < 4; ++r) {
                        int key = j0 + t * 16 + lq * 4 + r;
                        float pv = (key <= qi)
                                 ? __builtin_amdgcn_exp2f(st[t][r]) : 0.f;
                        st[t][r] = pv;
                        part += pv;
                    }
            }
            lrow += part;
            for (int t = 0; t < 4; ++t) {
                union { bf16 h4[4]; uint2 v; } pk;
                pk.h4[0] = __float2bfloat16(st[t][0]);
                pk.h4[1] = __float2bfloat16(st[t][1]);
                pk.h4[2] = __float2bfloat16(st[t][2]);
                pk.h4[3] = __float2bfloat16(st[t][3]);
                *(uint2*)&pw[wr_addr[t]] = pk.v;
            }
            asm volatile("s_waitcnt lgkmcnt(0)" ::: "memory");
            bf8v pb0 = *(const bf8v*)&pw[rd_addr[0]];
            bf8v pb1 = *(const bf8v*)&pw[rd_addr[1]];
            __builtin_amdgcn_s_setprio(1);
            for (int t = 0; t < 4; ++t) {
                o[t] = mfma_16x16x32(vf[t][0], pb0, o[t]);
                o[t] = mfma_16x16x32(vf[t][1], pb1, o[t]);
            }
            __builtin_amdgcn_s_setprio(0);
            asm volatile("s_barrier" ::: "memory");   // reads done -> next stage may overwrite
        }

        // ---- epilogue: reduce l across quads; O^T[d][q] -> O[b][q][h][d] ----
        {
            lrow += __shfl_xor(lrow, 16);
            lrow += __shfl_xor(lrow, 32);
            float inv = 1.0f / lrow;
            bf16* orow = O + ((long)(b * cS + qi) * cNH + h) * cDH;
            for (int t = 0; t < 4; ++t) {
                union { bf16 h4[4]; uint2 v; } pk;
                pk.h4[0] = __float2bfloat16(o[t][0] * inv);
                pk.h4[1] = __float2bfloat16(o[t][1] * inv);
                pk.h4[2] = __float2bfloat16(o[t][2] * inv);
                pk.h4[3] = __float2bfloat16(o[t][3] * inv);
                *(uint2*)(orow + t * 16 + lq * 4) = pk.v;
            }
        }
    }
}

// ---------------------------------------------------------------------------
// launcher
// ---------------------------------------------------------------------------
extern "C" void kernel_launch(void* const* d_in, const int* in_sizes, int n_in,
                              void* d_out, int out_size, void* d_ws, size_t ws_size,
                              hipStream_t stream) {
    const float* hs  = (const float*)d_in[0];
    const int*   pos = (const int*)d_in[1];
    const float* Wq  = (const float*)d_in[2];
    const float* Wk  = (const float*)d_in[3];
    const float* Wv  = (const float*)d_in[4];
    const float* Wo  = (const float*)d_in[5];
    float* out = (float*)d_out;
    char* ws = (char*)d_ws;

    // workspace layout (bytes)
    bf16* hsb = (bf16*)(ws + 0);              // [4096][2048]        16.78 MB
    bf16* WT  = (bf16*)(ws + 16777216);       // [3072][2048] fused QKV^T 12.58 MB
    bf16* WoT = (bf16*)(ws + 29360128);       // [2048][2048]         8.39 MB
    bf16* QKV = (bf16*)(ws + 37748736);       // [4096][3072]        25.17 MB
    bf16* VTb = (bf16*)(ws + 62914560);       // [2][8][64][2048]     4.19 MB
    bf16* AOb = (bf16*)(ws + 67108864);       // [4096][2048]        16.78 MB
    // total 83.9 MB

    dim3 tb(32, 8);

    // 1) hs -> bf16
    cvt_f32_bf16<<<8192, 256, 0, stream>>>(hs, hsb, (cB * cS * cH) / 4);
    // 2) weights -> fused B^T bf16 (rows: 0..2047 Wq, 2048..2559 Wk, 2560..3071 Wv)
    transpose_f32_bf16<<<dim3(64, 64), tb, 0, stream>>>(Wq, WT, 2048, 2048);
    transpose_f32_bf16<<<dim3(16, 64), tb, 0, stream>>>(Wk, WT + 2048 * 2048, 2048, 512);
    transpose_f32_bf16<<<dim3(16, 64), tb, 0, stream>>>(Wv, WT + 2560 * 2048, 2048, 512);
    transpose_f32_bf16<<<dim3(64, 64), tb, 0, stream>>>(Wo, WoT, 2048, 2048);
    // 3) fused QKV projection: [4096][3072] = hsb @ WT^T  (8-phase 256^2)
    gemm_bt8<bf16><<<dim3(16, 12), 512, 0, stream>>>(hsb, WT, QKV, 4096, cQKVW, 2048);
    // 4) RoPE in place on K only (Q-RoPE fused into attention)
    rope_kernel<<<4096, 256, 0, stream>>>(QKV + 2048, pos, 8, 3, cQKVW, 4096 * 8 * 32);
    // 5) V (cols 2560..3071) -> VT
    transpose_v<<<dim3(2, 64, 16), tb, 0, stream>>>(QKV + 2560, VTb);
    // 6) attention (1024 uniform blocks: 64q-tile pairs, 4 blocks/CU resident)
    attn_kernel<<<1024, 256, 0, stream>>>(QKV, VTb, pos, AOb);
    // 7) output projection -> fp32 d_out  (8-phase 256^2)
    gemm_bt8<float><<<dim3(16, 8), 512, 0, stream>>>(AOb, WoT, out, 4096, 2048, 2048);
}

// Round 6
// 339.952 us; speedup vs baseline: 1.0108x; 1.0108x over previous
//
#include <hip/hip_runtime.h>
#include <hip/hip_bf16.h>

// ---------------------------------------------------------------------------
// OptimizedAttention R9: fused QKV proj -> K-RoPE -> causal GQA flash attn
// -> output proj.
// R9: attn back to the R7 per-wave shape (4 waves x 32q; 16q waves were
// LDS-read-bound: same ds_read count per wave-step at half the work ->
// 2x LDS traffic ~ 70us floor, R8 measured 79.6). Scheduling replaced by
// PERSISTENT blocks + atomic queue: 768 blocks (3 x 40KB = 120KB -> 3
// blocks/CU guaranteed, 12 waves/CU vs R7's 8) pop 128q tiles heavy-first
// from a global counter (online LPT with refill -> no residency decay, no
// tail, no pairing needed). Queue counter at ws+0 (hsb region, dead after
// QKV GEMM), zeroed via hipMemsetAsync before attn.
// GEMMs: 256^2 8-phase schedule (R6, verified): T2 chunk-XOR swizzle +
// T3/T4 counted-vmcnt prefetch + T5 setprio; ledger in gemm_bt8 comment.
// B=2 S=2048 H=2048 NH=32 NKV=8 DH=64 N_REP=4 THETA=1e4
// ---------------------------------------------------------------------------

using bf16 = __hip_bfloat16;
typedef __attribute__((ext_vector_type(8))) __bf16 bf8v;   // MFMA A/B frag (4 VGPR)
typedef __attribute__((ext_vector_type(4))) float  f4v;    // MFMA C/D frag

#define AS1 __attribute__((address_space(1)))
#define AS3 __attribute__((address_space(3)))

constexpr int cB = 2, cS = 2048, cH = 2048, cNH = 32, cNKV = 8, cDH = 64;
constexpr int cQKVW = 3072;   // fused QKV row width (2048 Q + 512 K + 512 V)

template <int N> struct ic { static constexpr int value = N; };

__device__ __forceinline__ void async_cp16(const bf16* g, bf16* l) {
    __builtin_amdgcn_global_load_lds((const AS1 unsigned int*)(const void*)g,
                                     (AS3 unsigned int*)(void*)l, 16, 0, 0);
}

__device__ __forceinline__ f4v mfma_16x16x32(bf8v a, bf8v b, f4v c) {
    return __builtin_amdgcn_mfma_f32_16x16x32_bf16(a, b, c, 0, 0, 0);
}

__device__ __forceinline__ void store_out(float* p, float v) { *p = v; }
__device__ __forceinline__ void store_out(bf16*  p, float v) { *p = __float2bfloat16(v); }

// ---------------------------------------------------------------------------
__global__ void cvt_f32_bf16(const float* __restrict__ in, bf16* __restrict__ outp, int n4) {
    int i = blockIdx.x * 256 + threadIdx.x;
    if (i >= n4) return;
    float4 v = ((const float4*)in)[i];
    union { bf16 h[4]; uint2 u; } p;
    p.h[0] = __float2bfloat16(v.x);
    p.h[1] = __float2bfloat16(v.y);
    p.h[2] = __float2bfloat16(v.z);
    p.h[3] = __float2bfloat16(v.w);
    ((uint2*)outp)[i] = p.u;
}

// fp32 [R][C] -> bf16 [C][R] transpose-convert (weights -> B^T layout)
__global__ void transpose_f32_bf16(const float* __restrict__ in, bf16* __restrict__ outp,
                                   int R, int C) {
    __shared__ float tile[32][33];
    int c0 = blockIdx.x * 32, r0 = blockIdx.y * 32;
    int tx = threadIdx.x, ty = threadIdx.y;
    for (int i = ty; i < 32; i += 8)
        tile[i][tx] = in[(long)(r0 + i) * C + c0 + tx];
    __syncthreads();
    for (int i = ty; i < 32; i += 8)
        outp[(long)(c0 + i) * R + r0 + tx] = __float2bfloat16(tile[tx][i]);
}

// V slice of QKV [tok][3072] (cols 2560..3071) -> VT [B][NKV][DH][S]
__global__ void transpose_v(const bf16* __restrict__ Vsrc, bf16* __restrict__ VT) {
    __shared__ float tile[32][33];
    int z = blockIdx.z;               // b*NKV + kv
    int b = z >> 3, kv = z & 7;
    int d0 = blockIdx.x * 32, s0 = blockIdx.y * 32;
    int tx = threadIdx.x, ty = threadIdx.y;
    for (int i = ty; i < 32; i += 8)
        tile[i][tx] = __bfloat162float(Vsrc[(long)(b * cS + s0 + i) * cQKVW + kv * cDH + d0 + tx]);
    __syncthreads();
    for (int i = ty; i < 32; i += 8)
        VT[((long)(b * cNKV + kv) * cDH + d0 + i) * cS + s0 + tx] = __float2bfloat16(tile[tx][i]);
}

// In-place RoPE on bf16 rows of stride `rowstride`; pair (d, d+32), d<32.
__global__ void rope_kernel(bf16* __restrict__ X, const int* __restrict__ pos,
                            int nh, int hshift, int rowstride, int total) {
    int idx = blockIdx.x * 256 + threadIdx.x;
    if (idx >= total) return;
    int d   = idx & 31;
    int t2  = idx >> 5;
    int hh  = t2 & (nh - 1);
    int tok = t2 >> hshift;
    float p   = (float)pos[tok];
    float inv = __expf(-(float)(2 * d) * (1.0f / 64.0f) * 9.210340371976184f);
    float ang = p * inv;
    float s = sinf(ang), c = cosf(ang);
    long base = (long)tok * rowstride + hh * 64 + d;
    float x1 = __bfloat162float(X[base]);
    float x2 = __bfloat162float(X[base + 32]);
    X[base]      = __float2bfloat16(x1 * c - x2 * s);
    X[base + 32] = __float2bfloat16(x2 * c + x1 * s);
}

// ---------------------------------------------------------------------------
// bf16 GEMM, B-transposed, 256x256 tile, 8-phase deep-pipelined schedule.
// C[M][N] = A[M][K] * BT[N][K]^T.  M%256==0, N%256==0, K%64==0, K/64 >= 3.
// 512 threads = 8 waves (2M x 4N), wave tile 128x64, acc[8][4].
// LDS: 2 bufs x (A[256][64] + B[256][64]) bf16 = 128 KiB.
// Chunk-XOR swizzle: 16B chunk c of row r stored at slot c^(r&7); applied
// to the global SOURCE address (global_load_lds writes linearly) and to
// the ds_read address -- frag reads are 2 lanes/bank (conflict-free).
// Per K-tile (4 phases of {ds_read; prefetch-issue; barrier; lgkmcnt(0);
// setprio(1); 16 MFMA; setprio(0); [counted vmcnt]; barrier}):
//   ph0: issue A-u0(t+1)->buf^1   ph1: issue A-u1(t+1)->buf^1, vmcnt(8)
//   ph2: issue B-h0(t+2)->buf     ph3: issue B-h1(t+2)->buf,   vmcnt(6)
// B region of buf is dead after ph0 (read into regs, 2 barriers earlier),
// so B(t+2) staging into the live buffer is race-free. In-flight ledger
// at tile entry: {A-u1(t)[2], B(t+1)[4]} = 6 loads; waits keep the tile
// being read always fully landed, never draining to 0 mid-loop.
// ---------------------------------------------------------------------------
template <typename OutT>
__global__ __launch_bounds__(512)
void gemm_bt8(const bf16* __restrict__ A, const bf16* __restrict__ BT,
              OutT* __restrict__ C, int M, int N, int K) {
    __shared__ __align__(16) bf16 Al[2][256 * 64];   // 32 KB x2
    __shared__ __align__(16) bf16 Bl[2][256 * 64];   // 32 KB x2
    const int tid  = threadIdx.x;
    const int lane = tid & 63;
    const int wave = tid >> 6;
    const int wm = wave >> 2, wn = wave & 3;         // 2M x 4N wave grid
    const int lm = lane & 15, lq = lane >> 4;
    const int bm = blockIdx.x * 256, bn = blockIdx.y * 256;
    const int NT = K >> 6;                           // K-tiles of 64

    f4v acc[8][4];
    #pragma unroll
    for (int i = 0; i < 8; ++i)
        #pragma unroll
        for (int j = 0; j < 4; ++j)
            for (int r = 0; r < 4; ++r) acc[i][j][r] = 0.f;

    // ---- staging addressing -------------------------------------------------
    const bf16* aP[2][2]; const bf16* bP[2][2];
    int aD[2][2], bD[2][2];
    #pragma unroll
    for (int u = 0; u < 2; ++u)
        #pragma unroll
        for (int i = 0; i < 2; ++i) {
            int g = tid + i * 512;
            int ur = g >> 3, dc = g & 7;
            int row = ur + (ur & 64) + u * 64;
            int gch = dc ^ (row & 7);
            aP[u][i] = A + (long)(bm + row) * K + gch * 8;
            aD[u][i] = row * 64 + dc * 8;
        }
    #pragma unroll
    for (int h = 0; h < 2; ++h)
        #pragma unroll
        for (int i = 0; i < 2; ++i) {
            int g = tid + i * 512;
            int ur = g >> 3, dc = g & 7;
            int row = h * 128 + ur;
            int gch = dc ^ (row & 7);
            bP[h][i] = BT + (long)(bn + row) * K + gch * 8;
            bD[h][i] = row * 64 + dc * 8;
        }

    auto stageA = [&](int buf, int t, int u) {
        long ko = (long)t * 64;
        async_cp16(aP[u][0] + ko, &Al[buf][aD[u][0]]);
        async_cp16(aP[u][1] + ko, &Al[buf][aD[u][1]]);
    };
    auto stageB = [&](int buf, int t, int h) {
        long ko = (long)t * 64;
        async_cp16(bP[h][0] + ko, &Bl[buf][bD[h][0]]);
        async_cp16(bP[h][1] + ko, &Bl[buf][bD[h][1]]);
    };

    // ---- fragment read addressing (row&7 == lm&7 for all frag rows) --------
    const int x7 = lm & 7;
    const int co0 = (lq ^ x7) * 8;           // k-half 0: chunk lq
    const int co1 = ((4 + lq) ^ x7) * 8;     // k-half 1: chunk 4+lq
    const int abase = (wm * 128 + lm) * 64;
    const int bbase = (wn * 64 + lm) * 64;

    // ---- prologue: B(0), A-u0(0), A-u1(0), B(1); first 6 loads must land ---
    stageB(0, 0, 0); stageB(0, 0, 1); stageA(0, 0, 0); stageA(0, 0, 1);
    stageB(1, 1, 0); stageB(1, 1, 1);
    asm volatile("s_waitcnt vmcnt(6)" ::: "memory");  // B(0)+A-u0(0) landed
    asm volatile("s_barrier" ::: "memory");

    auto ktile = [&](int t, bool ia, bool ib, auto w1, auto w3) {
        const int cb = t & 1;
        const bf16* Ac = &Al[cb][0];
        const bf16* Bc = &Bl[cb][0];
        bf8v bfr[4][2];
        #pragma unroll
        for (int q = 0; q < 4; ++q) {
            bf8v afr[2][2];
            if (q == 0) {
                #pragma unroll
                for (int n = 0; n < 4; ++n) {
                    bfr[n][0] = *(const bf8v*)&Bc[bbase + n * 1024 + co0];
                    bfr[n][1] = *(const bf8v*)&Bc[bbase + n * 1024 + co1];
                }
            }
            #pragma unroll
            for (int i2 = 0; i2 < 2; ++i2) {
                afr[i2][0] = *(const bf8v*)&Ac[abase + (q * 2 + i2) * 1024 + co0];
                afr[i2][1] = *(const bf8v*)&Ac[abase + (q * 2 + i2) * 1024 + co1];
            }
            if (q == 0 && ia) stageA(cb ^ 1, t + 1, 0);
            if (q == 1 && ia) stageA(cb ^ 1, t + 1, 1);
            if (q == 2 && ib) stageB(cb, t + 2, 0);
            if (q == 3 && ib) stageB(cb, t + 2, 1);
            asm volatile("s_barrier" ::: "memory");
            asm volatile("s_waitcnt lgkmcnt(0)" ::: "memory");
            __builtin_amdgcn_s_setprio(1);
            #pragma unroll
            for (int i2 = 0; i2 < 2; ++i2)
                #pragma unroll
                for (int n = 0; n < 4; ++n) {
                    acc[q * 2 + i2][n] = mfma_16x16x32(afr[i2][0], bfr[n][0], acc[q * 2 + i2][n]);
                    acc[q * 2 + i2][n] = mfma_16x16x32(afr[i2][1], bfr[n][1], acc[q * 2 + i2][n]);
                }
            __builtin_amdgcn_s_setprio(0);
            if (q == 1) {
                if constexpr (decltype(w1)::value == 8)
                    asm volatile("s_waitcnt vmcnt(8)" ::: "memory");  // A-u1(t) landed
                else
                    asm volatile("s_waitcnt vmcnt(0)" ::: "memory");  // last tile drain
            }
            if (q == 3) {
                if constexpr (decltype(w3)::value == 1)
                    asm volatile("s_waitcnt vmcnt(6)" ::: "memory");  // B(t+1)+A-u0(t+1) landed
                else if constexpr (decltype(w3)::value == 2)
                    asm volatile("s_waitcnt vmcnt(2)" ::: "memory");  // peeled NT-2 boundary
            }
            asm volatile("s_barrier" ::: "memory");
        }
    };

    int t = 0;
    for (; t + 2 < NT; ++t) ktile(t, true, true, ic<8>{}, ic<1>{});
    ktile(t, true, false, ic<8>{}, ic<2>{});   // t = NT-2: no B(NT) issues
    ++t;
    ktile(t, false, false, ic<0>{}, ic<0>{});  // t = NT-1: drain A-u1 at ph1

    // ---- epilogue ----------------------------------------------------------
    #pragma unroll
    for (int mi = 0; mi < 8; ++mi) {
        int row = bm + wm * 128 + mi * 16 + lq * 4;
        #pragma unroll
        for (int n = 0; n < 4; ++n) {
            int col = bn + wn * 64 + n * 16 + lm;
            for (int r = 0; r < 4; ++r)
                store_out(&C[(long)(row + r) * N + col], acc[mi][n][r]);
        }
    }
}

// ---------------------------------------------------------------------------
// Causal GQA flash attention. PERSISTENT: 768 blocks (3 blocks/CU by LDS:
// 3 x 40KB = 120KB) pop 128-query tiles from a global atomic counter in
// heavy-first order (online LPT with refill -> steady 12 waves/CU, no
// tail). Tile ord 0..1023: qblk = 15-(ord>>6) (heavy first), combo =
// ord&63 -> (b,kvh,rep). Per tile: 4 waves x 32 queries, R7-verified step
// body: K/VT tiles async-staged to LDS (XOR-swizzled source chunks),
// double-buffered, raw s_barrier + vmcnt(4); fixed-base exp2 softmax
// (scale/ln2 folded into Q); Q-RoPE fused; setprio around MFMA.
// s_ord broadcast race-free: every wave reads it right after
// __syncthreads(); tid0 can't rewrite until all waves passed the tile's
// step barriers.
// ---------------------------------------------------------------------------
__global__ __launch_bounds__(256)
void attn_kernel(const bf16* __restrict__ QKV, const bf16* __restrict__ VT,
                 const int* __restrict__ pos, bf16* __restrict__ O,
                 int* __restrict__ ctr) {
    __shared__ __align__(16) bf16 Kl[2][64 * 64];   // [buf][key][dh]   8KB x2
    __shared__ __align__(16) bf16 Vl[2][64 * 64];   // [buf][d][key]    8KB x2
    __shared__ __align__(16) bf16 Pl[4][16 * 64];   // per-wave P tile  2KB x4
    __shared__ int s_ord;
    const int tid  = threadIdx.x;
    const int wave = tid >> 6, lane = tid & 63;
    const int lm = lane & 15, lq = lane >> 4;

    constexpr float SCALE = 0.18033688011112042f;

    // ---- tile-independent addressing ----
    bf16* pw = &Pl[wave][0];
    const int x7 = lm & 7;
    int wr_addr[4], rd_addr[2];
    for (int t = 0; t < 4; ++t)
        wr_addr[t] = lm * 64 + (((t * 2 + (lq >> 1)) ^ x7) * 8) + (lq & 1) * 4;
    for (int c = 0; c < 2; ++c)
        rd_addr[c] = lm * 64 + (((c * 4 + lq) ^ x7) * 8);

    const int srow = tid >> 3, sch = tid & 7;
    const int sc8 = (sch ^ (srow & 7)) * 8;    // (32+srow)&7 == srow&7

    while (true) {
        if (tid == 0) s_ord = atomicAdd(ctr, 1);
        __syncthreads();
        const int ord = s_ord;
        if (ord >= 1024) break;

        const int qblk = 15 - (ord >> 6);           // heavy tiles first
        const int combo = ord & 63;
        const int kvh = combo & 7;
        const int rep = (combo >> 3) & 3;
        const int b   = combo >> 5;
        const int h = kvh * 4 + rep;
        const int q0 = qblk * 128;
        const int qw = q0 + wave * 32;              // this wave's 32 queries
        const int nsteps = 2 * qblk + 2;

        // per-tile staging pointers
        const bf16* kgb = QKV + (long)b * cS * cQKVW + 2048 + kvh * cDH;
        const bf16* vgb = VT + (long)(b * cNKV + kvh) * cDH * cS;
        const bf16* kp0 = kgb + (long)srow * cQKVW + sc8;
        const bf16* kp1 = kgb + (long)(32 + srow) * cQKVW + sc8;
        const bf16* vp0 = vgb + (long)srow * cS + sc8;
        const bf16* vp1 = vgb + (long)(32 + srow) * cS + sc8;
        auto stage = [&](int buf, int j0) {
            long ko = (long)j0 * cQKVW;
            async_cp16(kp0 + ko, &Kl[buf][tid * 8]);
            async_cp16(kp1 + ko, &Kl[buf][2048 + tid * 8]);
            async_cp16(vp0 + j0, &Vl[buf][tid * 8]);
            async_cp16(vp1 + j0, &Vl[buf][2048 + tid * 8]);
        };

        // ---- Q fragments (B-frag: n=q=lm, k=dh=lq*8+j), RoPE + scale fused
        bf8v qf[2][2];
        for (int u = 0; u < 2; ++u) {
            const int qi = qw + u * 16 + lm;
            const bf16* qrow = QKV + (long)(b * cS + qi) * cQKVW + h * cDH;
            float p = (float)pos[b * cS + qi];
            bf8v r0 = *(const bf8v*)(qrow + lq * 8);
            bf8v r1 = *(const bf8v*)(qrow + 32 + lq * 8);
            bf8v t0, t1;
            for (int j = 0; j < 8; ++j) {
                int d = lq * 8 + j;
                float inv = __expf(-(float)(2 * d) * (1.0f / 64.0f) * 9.210340371976184f);
                float sn, cs;
                __sincosf(p * inv, &sn, &cs);
                float a = (float)r0[j], c2 = (float)r1[j];
                t0[j] = (__bf16)((a * cs - c2 * sn) * SCALE);
                t1[j] = (__bf16)((c2 * cs + a * sn) * SCALE);
            }
            qf[u][0] = t0; qf[u][1] = t1;
        }

        float lrow[2] = {0.f, 0.f};
        f4v o[2][4];
        for (int u = 0; u < 2; ++u)
            for (int t = 0; t < 4; ++t)
                for (int r = 0; r < 4; ++r) o[u][t][r] = 0.f;

        stage(0, 0);
        for (int step = 0; step < nsteps; ++step) {
            const int j0 = step * 64;
            const int cur = step & 1;
            if (step + 1 < nsteps) {
                stage(cur ^ 1, j0 + 64);
                asm volatile("s_waitcnt vmcnt(4)" ::: "memory");  // current tile only
            } else {
                asm volatile("s_waitcnt vmcnt(0)" ::: "memory");
            }
            asm volatile("s_barrier" ::: "memory");

            if (qw + 31 >= j0) {   // wave-uniform; skip fully-masked steps
                f4v st[2][4];
                for (int u = 0; u < 2; ++u)
                    for (int t = 0; t < 4; ++t)
                        for (int r = 0; r < 4; ++r) st[u][t][r] = 0.f;
                __builtin_amdgcn_s_setprio(1);
                for (int t = 0; t < 4; ++t) {
                    int kr = t * 16 + lm;
                    bf8v kf0 = *(const bf8v*)&Kl[cur][kr * 64 + ((lq ^ (kr & 7)) * 8)];
                    bf8v kf1 = *(const bf8v*)&Kl[cur][kr * 64 + (((4 + lq) ^ (kr & 7)) * 8)];
                    for (int u = 0; u < 2; ++u) {
                        st[u][t] = mfma_16x16x32(kf0, qf[u][0], st[u][t]);
                        st[u][t] = mfma_16x16x32(kf1, qf[u][1], st[u][t]);
                    }
                }
                __builtin_amdgcn_s_setprio(0);
                bf8v vf[4][2];
                for (int t = 0; t < 4; ++t) {
                    int vr = t * 16 + lm;
                    vf[t][0] = *(const bf8v*)&Vl[cur][vr * 64 + ((lq ^ (vr & 7)) * 8)];
                    vf[t][1] = *(const bf8v*)&Vl[cur][vr * 64 + (((4 + lq) ^ (vr & 7)) * 8)];
                }
                const bool full = (j0 + 63 <= qw);
                for (int u = 0; u < 2; ++u) {
                    float part = 0.f;
                    if (full) {
                        for (int t = 0; t < 4; ++t)
                            for (int r = 0; r < 4; ++r) {
                                float pv = __builtin_amdgcn_exp2f(st[u][t][r]);
                                st[u][t][r] = pv;
                                part += pv;
                            }
                    } else {
                        const int qi = qw + u * 16 + lm;
                        for (int t = 0; t < 4; ++t)
                            for (int r = 0; r < 4; ++r) {
                                int key = j0 + t * 16 + lq * 4 + r;
                                float pv = (key <= qi)
                                         ? __builtin_amdgcn_exp2f(st[u][t][r]) : 0.f;
                                st[u][t][r] = pv;
                                part += pv;
                            }
                    }
                    lrow[u] += part;
                    for (int t = 0; t < 4; ++t) {
                        union { bf16 h4[4]; uint2 v; } pk;
                        pk.h4[0] = __float2bfloat16(st[u][t][0]);
                        pk.h4[1] = __float2bfloat16(st[u][t][1]);
                        pk.h4[2] = __float2bfloat16(st[u][t][2]);
                        pk.h4[3] = __float2bfloat16(st[u][t][3]);
                        *(uint2*)&pw[wr_addr[t]] = pk.v;
                    }
                    asm volatile("s_waitcnt lgkmcnt(0)" ::: "memory");
                    bf8v pb0 = *(const bf8v*)&pw[rd_addr[0]];
                    bf8v pb1 = *(const bf8v*)&pw[rd_addr[1]];
                    __builtin_amdgcn_s_setprio(1);
                    for (int t = 0; t < 4; ++t) {
                        o[u][t] = mfma_16x16x32(vf[t][0], pb0, o[u][t]);
                        o[u][t] = mfma_16x16x32(vf[t][1], pb1, o[u][t]);
                    }
                    __builtin_amdgcn_s_setprio(0);
                }
            }
            asm volatile("s_barrier" ::: "memory");   // reads done -> next stage may overwrite
        }

        // ---- epilogue: reduce l across quads; O^T[d][q] -> O[b][q][h][d] ----
        for (int u = 0; u < 2; ++u) {
            lrow[u] += __shfl_xor(lrow[u], 16);
            lrow[u] += __shfl_xor(lrow[u], 32);
            float inv = 1.0f / lrow[u];
            const int qi = qw + u * 16 + lm;
            bf16* orow = O + ((long)(b * cS + qi) * cNH + h) * cDH;
            for (int t = 0; t < 4; ++t) {
                union { bf16 h4[4]; uint2 v; } pk;
                pk.h4[0] = __float2bfloat16(o[u][t][0] * inv);
                pk.h4[1] = __float2bfloat16(o[u][t][1] * inv);
                pk.h4[2] = __float2bfloat16(o[u][t][2] * inv);
                pk.h4[3] = __float2bfloat16(o[u][t][3] * inv);
                *(uint2*)(orow + t * 16 + lq * 4) = pk.v;
            }
        }
    }
}

// ---------------------------------------------------------------------------
// launcher
// ---------------------------------------------------------------------------
extern "C" void kernel_launch(void* const* d_in, const int* in_sizes, int n_in,
                              void* d_out, int out_size, void* d_ws, size_t ws_size,
                              hipStream_t stream) {
    const float* hs  = (const float*)d_in[0];
    const int*   pos = (const int*)d_in[1];
    const float* Wq  = (const float*)d_in[2];
    const float* Wk  = (const float*)d_in[3];
    const float* Wv  = (const float*)d_in[4];
    const float* Wo  = (const float*)d_in[5];
    float* out = (float*)d_out;
    char* ws = (char*)d_ws;

    // workspace layout (bytes)
    bf16* hsb = (bf16*)(ws + 0);              // [4096][2048]        16.78 MB
    bf16* WT  = (bf16*)(ws + 16777216);       // [3072][2048] fused QKV^T 12.58 MB
    bf16* WoT = (bf16*)(ws + 29360128);       // [2048][2048]         8.39 MB
    bf16* QKV = (bf16*)(ws + 37748736);       // [4096][3072]        25.17 MB
    bf16* VTb = (bf16*)(ws + 62914560);       // [2][8][64][2048]     4.19 MB
    bf16* AOb = (bf16*)(ws + 67108864);       // [4096][2048]        16.78 MB
    int*  ctr = (int*)ws;                     // attn work-queue counter
    // (hsb region is dead after the QKV GEMM; ctr reuses its first 4 bytes)

    dim3 tb(32, 8);

    // 1) hs -> bf16
    cvt_f32_bf16<<<8192, 256, 0, stream>>>(hs, hsb, (cB * cS * cH) / 4);
    // 2) weights -> fused B^T bf16 (rows: 0..2047 Wq, 2048..2559 Wk, 2560..3071 Wv)
    transpose_f32_bf16<<<dim3(64, 64), tb, 0, stream>>>(Wq, WT, 2048, 2048);
    transpose_f32_bf16<<<dim3(16, 64), tb, 0, stream>>>(Wk, WT + 2048 * 2048, 2048, 512);
    transpose_f32_bf16<<<dim3(16, 64), tb, 0, stream>>>(Wv, WT + 2560 * 2048, 2048, 512);
    transpose_f32_bf16<<<dim3(64, 64), tb, 0, stream>>>(Wo, WoT, 2048, 2048);
    // 3) fused QKV projection: [4096][3072] = hsb @ WT^T  (8-phase 256^2)
    gemm_bt8<bf16><<<dim3(16, 12), 512, 0, stream>>>(hsb, WT, QKV, 4096, cQKVW, 2048);
    // 4) RoPE in place on K only (Q-RoPE fused into attention)
    rope_kernel<<<4096, 256, 0, stream>>>(QKV + 2048, pos, 8, 3, cQKVW, 4096 * 8 * 32);
    // 5) V (cols 2560..3071) -> VT
    transpose_v<<<dim3(2, 64, 16), tb, 0, stream>>>(QKV + 2560, VTb);
    // 6) attention: persistent 768 blocks, atomic heavy-first work queue
    hipMemsetAsync(ctr, 0, sizeof(int), stream);
    attn_kernel<<<768, 256, 0, stream>>>(QKV, VTb, pos, AOb, ctr);
    // 7) output projection -> fp32 d_out  (8-phase 256^2)
    gemm_bt8<float><<<dim3(16, 8), 512, 0, stream>>>(AOb, WoT, out, 4096, 2048, 2048);
}

// Round 7
// 321.619 us; speedup vs baseline: 1.0685x; 1.0570x over previous
//
#include <hip/hip_runtime.h>
#include <hip/hip_bf16.h>

// ---------------------------------------------------------------------------
// OptimizedAttention R10: 4-dispatch pipeline.
// R9 post-mortem: scheduling experiments (R8 16q-waves, R9 persistent+queue)
// both failed; occupancy pinned ~19% regardless. Meanwhile the time budget
// shows ~120us of inter-dispatch gaps (10 launches x ~10us) vs ~215us of
// kernel time. R10 attacks the gaps:
//   1) prep_kernel: hs->bf16 cvt + all 4 weight transposes in ONE kernel.
//   2) gemm_bt8_qkv: K-RoPE fused into the QKV GEMM epilogue (pairs (d,d+32)
//      are lane-local: acc[mi][n] <-> acc[mi][n+2]); V-cols written directly
//      to VT (transposed) from acc. rope_kernel + transpose_v eliminated.
//   3) attn: R7 version verbatim (best measured, 72.4us: 512 blocks, 4 waves
//      x 32q, paired q-tiles p/15-p = uniform 34 steps, XCD affinity).
//   4) outproj gemm unchanged (8-phase 256^2).
// Dispatches: prep -> gemm_qkv -> attn -> gemm_out  (was 10).
// GEMM schedule (R6-verified): T2 chunk-XOR swizzle + T3/T4 counted-vmcnt
// deep prefetch + T5 setprio; staging ledger in gemm comment.
// B=2 S=2048 H=2048 NH=32 NKV=8 DH=64 N_REP=4 THETA=1e4
// ---------------------------------------------------------------------------

using bf16 = __hip_bfloat16;
typedef __attribute__((ext_vector_type(8))) __bf16 bf8v;   // MFMA A/B frag (4 VGPR)
typedef __attribute__((ext_vector_type(4))) float  f4v;    // MFMA C/D frag

#define AS1 __attribute__((address_space(1)))
#define AS3 __attribute__((address_space(3)))

constexpr int cB = 2, cS = 2048, cH = 2048, cNH = 32, cNKV = 8, cDH = 64;
constexpr int cQKVW = 3072;   // fused QKV row width (2048 Q + 512 K + 512 V)

template <int N> struct ic { static constexpr int value = N; };

__device__ __forceinline__ void async_cp16(const bf16* g, bf16* l) {
    __builtin_amdgcn_global_load_lds((const AS1 unsigned int*)(const void*)g,
                                     (AS3 unsigned int*)(void*)l, 16, 0, 0);
}

__device__ __forceinline__ f4v mfma_16x16x32(bf8v a, bf8v b, f4v c) {
    return __builtin_amdgcn_mfma_f32_16x16x32_bf16(a, b, c, 0, 0, 0);
}

__device__ __forceinline__ void store_out(float* p, float v) { *p = v; }
__device__ __forceinline__ void store_out(bf16*  p, float v) { *p = __float2bfloat16(v); }

// ---------------------------------------------------------------------------
// prep: fused  hs->bf16 cvt  +  4 weight transposes (f32 [R][C] -> bf16 [C][R])
// grid: [0,8192) cvt blocks; [8192,18432) transpose tile-blocks:
//   Wq 4096 tiles -> WT rows 0..2047 ; Wk 1024 -> WT+2048*2048 ;
//   Wv 1024 -> WT+2560*2048 ; Wo 4096 -> WoT.
// ---------------------------------------------------------------------------
__global__ void prep_kernel(const float* __restrict__ hs, bf16* __restrict__ hsb,
                            const float* __restrict__ Wq, const float* __restrict__ Wk,
                            const float* __restrict__ Wv, const float* __restrict__ Wo,
                            bf16* __restrict__ WT, bf16* __restrict__ WoT) {
    __shared__ float tile[32][33];
    const int bz = blockIdx.x, tid = threadIdx.x;
    if (bz < 8192) {
        int i = bz * 256 + tid;
        float4 v = ((const float4*)hs)[i];
        union { bf16 h[4]; uint2 u; } p;
        p.h[0] = __float2bfloat16(v.x);
        p.h[1] = __float2bfloat16(v.y);
        p.h[2] = __float2bfloat16(v.z);
        p.h[3] = __float2bfloat16(v.w);
        ((uint2*)hsb)[i] = p.u;
        return;
    }
    const int t = bz - 8192;
    const float* in; bf16* outp; int C, x, y;
    if (t < 4096)      { in = Wq; outp = WT;               C = 2048; x = t & 63; y = t >> 6; }
    else if (t < 5120) { int l = t - 4096; in = Wk; outp = WT + 2048 * 2048; C = 512; x = l & 15; y = l >> 4; }
    else if (t < 6144) { int l = t - 5120; in = Wv; outp = WT + 2560 * 2048; C = 512; x = l & 15; y = l >> 4; }
    else               { int l = t - 6144; in = Wo; outp = WoT;             C = 2048; x = l & 63; y = l >> 6; }
    const int c0 = x * 32, r0 = y * 32;
    const int tx = tid & 31, ty = tid >> 5;
    for (int i = ty; i < 32; i += 8)
        tile[i][tx] = in[(long)(r0 + i) * C + c0 + tx];
    __syncthreads();
    for (int i = ty; i < 32; i += 8)
        outp[(long)(c0 + i) * 2048 + r0 + tx] = __float2bfloat16(tile[tx][i]);
}

// ---------------------------------------------------------------------------
// bf16 GEMM, B-transposed, 256x256 tile, 8-phase deep-pipelined schedule.
// C[M][N] = A[M][K] * BT[N][K]^T.  Schedule/ledger (R6-verified):
// Per K-tile t (4 phases of {ds_read; prefetch-issue; barrier; lgkmcnt(0);
// setprio(1); 16 MFMA; setprio(0); [counted vmcnt]; barrier}):
//   ph0: issue A-u0(t+1)->buf^1   ph1: issue A-u1(t+1)->buf^1, vmcnt(8)
//   ph2: issue B-h0(t+2)->buf     ph3: issue B-h1(t+2)->buf,   vmcnt(6)
// B region of buf is dead after ph0; in-flight ledger at tile entry:
// {A-u1(t)[2], B(t+1)[4]} = 6 loads; never drains to 0 mid-loop.
// Chunk-XOR swizzle c^=(row&7) on global SOURCE + ds_read (conflict-free).
// ---------------------------------------------------------------------------
#define GEMM_CORE(AARG, BTARG, KARG)                                            \
    __shared__ __align__(16) bf16 Al[2][256 * 64];                              \
    __shared__ __align__(16) bf16 Bl[2][256 * 64];                              \
    const int tid  = threadIdx.x;                                               \
    const int lane = tid & 63;                                                  \
    const int wave = tid >> 6;                                                  \
    const int wm = wave >> 2, wn = wave & 3;                                    \
    const int lm = lane & 15, lq = lane >> 4;                                   \
    const int bm = blockIdx.x * 256, bn = blockIdx.y * 256;                     \
    const int NT = (KARG) >> 6;                                                 \
    f4v acc[8][4];                                                              \
    _Pragma("unroll")                                                           \
    for (int i = 0; i < 8; ++i)                                                 \
        _Pragma("unroll")                                                       \
        for (int j = 0; j < 4; ++j)                                             \
            for (int r = 0; r < 4; ++r) acc[i][j][r] = 0.f;                     \
    const bf16* aP[2][2]; const bf16* bP[2][2];                                 \
    int aD[2][2], bD[2][2];                                                     \
    _Pragma("unroll")                                                           \
    for (int u = 0; u < 2; ++u)                                                 \
        _Pragma("unroll")                                                       \
        for (int i = 0; i < 2; ++i) {                                           \
            int g = tid + i * 512;                                              \
            int ur = g >> 3, dc = g & 7;                                        \
            int row = ur + (ur & 64) + u * 64;                                  \
            int gch = dc ^ (row & 7);                                           \
            aP[u][i] = (AARG) + (long)(bm + row) * (KARG) + gch * 8;            \
            aD[u][i] = row * 64 + dc * 8;                                       \
        }                                                                       \
    _Pragma("unroll")                                                           \
    for (int h = 0; h < 2; ++h)                                                 \
        _Pragma("unroll")                                                       \
        for (int i = 0; i < 2; ++i) {                                           \
            int g = tid + i * 512;                                              \
            int ur = g >> 3, dc = g & 7;                                        \
            int row = h * 128 + ur;                                             \
            int gch = dc ^ (row & 7);                                           \
            bP[h][i] = (BTARG) + (long)(bn + row) * (KARG) + gch * 8;           \
            bD[h][i] = row * 64 + dc * 8;                                       \
        }                                                                       \
    auto stageA = [&](int buf, int t, int u) {                                  \
        long ko = (long)t * 64;                                                 \
        async_cp16(aP[u][0] + ko, &Al[buf][aD[u][0]]);                          \
        async_cp16(aP[u][1] + ko, &Al[buf][aD[u][1]]);                          \
    };                                                                          \
    auto stageB = [&](int buf, int t, int h) {                                  \
        long ko = (long)t * 64;                                                 \
        async_cp16(bP[h][0] + ko, &Bl[buf][bD[h][0]]);                          \
        async_cp16(bP[h][1] + ko, &Bl[buf][bD[h][1]]);                          \
    };                                                                          \
    const int x7 = lm & 7;                                                      \
    const int co0 = (lq ^ x7) * 8;                                              \
    const int co1 = ((4 + lq) ^ x7) * 8;                                        \
    const int abase = (wm * 128 + lm) * 64;                                     \
    const int bbase = (wn * 64 + lm) * 64;                                      \
    stageB(0, 0, 0); stageB(0, 0, 1); stageA(0, 0, 0); stageA(0, 0, 1);         \
    stageB(1, 1, 0); stageB(1, 1, 1);                                           \
    asm volatile("s_waitcnt vmcnt(6)" ::: "memory");                            \
    asm volatile("s_barrier" ::: "memory");                                     \
    auto ktile = [&](int t, bool ia, bool ib, auto w1, auto w3) {               \
        const int cb = t & 1;                                                   \
        const bf16* Ac = &Al[cb][0];                                            \
        const bf16* Bc = &Bl[cb][0];                                            \
        bf8v bfr[4][2];                                                         \
        _Pragma("unroll")                                                       \
        for (int q = 0; q < 4; ++q) {                                           \
            bf8v afr[2][2];                                                     \
            if (q == 0) {                                                       \
                _Pragma("unroll")                                               \
                for (int n = 0; n < 4; ++n) {                                   \
                    bfr[n][0] = *(const bf8v*)&Bc[bbase + n * 1024 + co0];      \
                    bfr[n][1] = *(const bf8v*)&Bc[bbase + n * 1024 + co1];      \
                }                                                               \
            }                                                                   \
            _Pragma("unroll")                                                   \
            for (int i2 = 0; i2 < 2; ++i2) {                                    \
                afr[i2][0] = *(const bf8v*)&Ac[abase + (q * 2 + i2) * 1024 + co0]; \
                afr[i2][1] = *(const bf8v*)&Ac[abase + (q * 2 + i2) * 1024 + co1]; \
            }                                                                   \
            if (q == 0 && ia) stageA(cb ^ 1, t + 1, 0);                         \
            if (q == 1 && ia) stageA(cb ^ 1, t + 1, 1);                         \
            if (q == 2 && ib) stageB(cb, t + 2, 0);                             \
            if (q == 3 && ib) stageB(cb, t + 2, 1);                             \
            asm volatile("s_barrier" ::: "memory");                             \
            asm volatile("s_waitcnt lgkmcnt(0)" ::: "memory");                  \
            __builtin_amdgcn_s_setprio(1);                                      \
            _Pragma("unroll")                                                   \
            for (int i2 = 0; i2 < 2; ++i2)                                      \
                _Pragma("unroll")                                               \
                for (int n = 0; n < 4; ++n) {                                   \
                    acc[q * 2 + i2][n] = mfma_16x16x32(afr[i2][0], bfr[n][0], acc[q * 2 + i2][n]); \
                    acc[q * 2 + i2][n] = mfma_16x16x32(afr[i2][1], bfr[n][1], acc[q * 2 + i2][n]); \
                }                                                               \
            __builtin_amdgcn_s_setprio(0);                                      \
            if (q == 1) {                                                       \
                if constexpr (decltype(w1)::value == 8)                         \
                    asm volatile("s_waitcnt vmcnt(8)" ::: "memory");            \
                else                                                            \
                    asm volatile("s_waitcnt vmcnt(0)" ::: "memory");            \
            }                                                                   \
            if (q == 3) {                                                       \
                if constexpr (decltype(w3)::value == 1)                         \
                    asm volatile("s_waitcnt vmcnt(6)" ::: "memory");            \
                else if constexpr (decltype(w3)::value == 2)                    \
                    asm volatile("s_waitcnt vmcnt(2)" ::: "memory");            \
            }                                                                   \
            asm volatile("s_barrier" ::: "memory");                             \
        }                                                                       \
    };                                                                          \
    {                                                                           \
        int t = 0;                                                              \
        for (; t + 2 < NT; ++t) ktile(t, true, true, ic<8>{}, ic<1>{});         \
        ktile(t, true, false, ic<8>{}, ic<2>{});                                \
        ++t;                                                                    \
        ktile(t, false, false, ic<0>{}, ic<0>{});                               \
    }

// Generic (outproj) variant: plain epilogue.
template <typename OutT>
__global__ __launch_bounds__(512)
void gemm_bt8(const bf16* __restrict__ A, const bf16* __restrict__ BT,
              OutT* __restrict__ C, int M, int N, int K) {
    GEMM_CORE(A, BT, K)
    #pragma unroll
    for (int mi = 0; mi < 8; ++mi) {
        int row = bm + wm * 128 + mi * 16 + lq * 4;
        #pragma unroll
        for (int n = 0; n < 4; ++n) {
            int col = bn + wn * 64 + n * 16 + lm;
            for (int r = 0; r < 4; ++r)
                store_out(&C[(long)(row + r) * N + col], acc[mi][n][r]);
        }
    }
}

// QKV variant: blockIdx.y 0..7 = Q (plain store), 8..9 = K (fused RoPE),
// 10..11 = V (transposed store into VT[b][kv][d][tok]).
// RoPE pairs (d, d+32) are lane-local: acc[mi][n] pairs with acc[mi][n+2]
// (d = n*16+lm for n=0,1). pos index = global row (b*S + tok).
__global__ __launch_bounds__(512)
void gemm_bt8_qkv(const bf16* __restrict__ A, const bf16* __restrict__ BT,
                  bf16* __restrict__ C, const int* __restrict__ pos,
                  bf16* __restrict__ VTout, int M, int N, int K) {
    GEMM_CORE(A, BT, K)
    const int yb = blockIdx.y;
    if (yb < 8) {
        #pragma unroll
        for (int mi = 0; mi < 8; ++mi) {
            int row = bm + wm * 128 + mi * 16 + lq * 4;
            #pragma unroll
            for (int n = 0; n < 4; ++n) {
                int col = bn + wn * 64 + n * 16 + lm;
                for (int r = 0; r < 4; ++r)
                    C[(long)(row + r) * N + col] = __float2bfloat16(acc[mi][n][r]);
            }
        }
    } else if (yb < 10) {
        #pragma unroll
        for (int mi = 0; mi < 8; ++mi) {
            int row = bm + wm * 128 + mi * 16 + lq * 4;
            float pr[4];
            for (int r = 0; r < 4; ++r) pr[r] = (float)pos[row + r];
            #pragma unroll
            for (int n = 0; n < 2; ++n) {
                int d = n * 16 + lm;
                float inv = __expf(-(float)(2 * d) * (1.0f / 64.0f) * 9.210340371976184f);
                int col = bn + wn * 64 + n * 16 + lm;
                for (int r = 0; r < 4; ++r) {
                    float a  = acc[mi][n][r];
                    float c2 = acc[mi][n + 2][r];
                    float sn, cs;
                    __sincosf(pr[r] * inv, &sn, &cs);
                    C[(long)(row + r) * N + col]      = __float2bfloat16(a * cs - c2 * sn);
                    C[(long)(row + r) * N + col + 32] = __float2bfloat16(c2 * cs + a * sn);
                }
            }
        }
    } else {
        #pragma unroll
        for (int mi = 0; mi < 8; ++mi) {
            int row = bm + wm * 128 + mi * 16 + lq * 4;
            int b = row >> 11, tok = row & 2047;
            #pragma unroll
            for (int n = 0; n < 4; ++n) {
                int vc = bn + wn * 64 + n * 16 + lm - 2560;
                int kv = vc >> 6, d = vc & 63;
                union { bf16 h4[4]; uint2 v; } pk;
                pk.h4[0] = __float2bfloat16(acc[mi][n][0]);
                pk.h4[1] = __float2bfloat16(acc[mi][n][1]);
                pk.h4[2] = __float2bfloat16(acc[mi][n][2]);
                pk.h4[3] = __float2bfloat16(acc[mi][n][3]);
                *(uint2*)&VTout[((long)(b * 8 + kv) * 64 + d) * 2048 + tok] = pk.v;
            }
        }
    }
}

// ---------------------------------------------------------------------------
// Causal GQA flash attention (R7 verbatim -- best measured). 512 blocks;
// block = (pair p, rep, b, kvh). Two sequential 128-query passes: q-tiles
// (15-p) then p -> exactly 34 key-steps per block (uniform). 4 waves x 32
// queries. Per 64-key step: K/VT tiles async-staged to LDS (XOR-swizzled
// source chunks), double-buffered, raw s_barrier + vmcnt(4). Fixed-base
// exp2 softmax (scale/ln2 folded into Q); Q-RoPE fused; setprio around
// MFMA. XCD affinity: idx&7 = kvh.
// ---------------------------------------------------------------------------
__global__ __launch_bounds__(256)
void attn_kernel(const bf16* __restrict__ QKV, const bf16* __restrict__ VT,
                 const int* __restrict__ pos, bf16* __restrict__ O) {
    __shared__ __align__(16) bf16 Kl[2][64 * 64];   // [buf][key][dh]   8KB x2
    __shared__ __align__(16) bf16 Vl[2][64 * 64];   // [buf][d][key]    8KB x2
    __shared__ __align__(16) bf16 Pl[4][16 * 64];   // per-wave P tile  2KB x4
    const int tid  = threadIdx.x;
    const int wave = tid >> 6, lane = tid & 63;
    const int lm = lane & 15, lq = lane >> 4;
    const int idx = blockIdx.x;
    const int pair = idx >> 6;                      // 0..7
    const int bh2 = idx & 15;
    const int rep = (idx >> 4) & 3;
    const int b = bh2 >> 3, kvh = bh2 & 7;
    const int h = kvh * 4 + rep;

    constexpr float SCALE = 0.18033688011112042f;

    bf16* pw = &Pl[wave][0];
    const int x7 = lm & 7;
    int wr_addr[4], rd_addr[2];
    for (int t = 0; t < 4; ++t)
        wr_addr[t] = lm * 64 + (((t * 2 + (lq >> 1)) ^ x7) * 8) + (lq & 1) * 4;
    for (int c = 0; c < 2; ++c)
        rd_addr[c] = lm * 64 + (((c * 4 + lq) ^ x7) * 8);

    const int srow = tid >> 3, sch = tid & 7;
    const bf16* kgb = QKV + (long)b * cS * cQKVW + 2048 + kvh * cDH;
    const bf16* vgb = VT + (long)(b * cNKV + kvh) * cDH * cS;
    const int sc8 = (sch ^ (srow & 7)) * 8;    // (32+srow)&7 == srow&7
    const bf16* kp0 = kgb + (long)srow * cQKVW + sc8;
    const bf16* kp1 = kgb + (long)(32 + srow) * cQKVW + sc8;
    const bf16* vp0 = vgb + (long)srow * cS + sc8;
    const bf16* vp1 = vgb + (long)(32 + srow) * cS + sc8;
    auto stage = [&](int buf, int j0) {
        long ko = (long)j0 * cQKVW;
        async_cp16(kp0 + ko, &Kl[buf][tid * 8]);
        async_cp16(kp1 + ko, &Kl[buf][2048 + tid * 8]);
        async_cp16(vp0 + j0, &Vl[buf][tid * 8]);
        async_cp16(vp1 + j0, &Vl[buf][2048 + tid * 8]);
    };

    for (int pass = 0; pass < 2; ++pass) {
        const int qblk = pass ? pair : 15 - pair;   // heavy pass first
        const int q0 = qblk * 128;
        const int qw = q0 + wave * 32;              // this wave's 32 queries
        const int nsteps = 2 * qblk + 2;

        bf8v qf[2][2];
        for (int u = 0; u < 2; ++u) {
            const int qi = qw + u * 16 + lm;
            const bf16* qrow = QKV + (long)(b * cS + qi) * cQKVW + h * cDH;
            float p = (float)pos[b * cS + qi];
            bf8v r0 = *(const bf8v*)(qrow + lq * 8);
            bf8v r1 = *(const bf8v*)(qrow + 32 + lq * 8);
            bf8v t0, t1;
            for (int j = 0; j < 8; ++j) {
                int d = lq * 8 + j;
                float inv = __expf(-(float)(2 * d) * (1.0f / 64.0f) * 9.210340371976184f);
                float sn, cs;
                __sincosf(p * inv, &sn, &cs);
                float a = (float)r0[j], c2 = (float)r1[j];
                t0[j] = (__bf16)((a * cs - c2 * sn) * SCALE);
                t1[j] = (__bf16)((c2 * cs + a * sn) * SCALE);
            }
            qf[u][0] = t0; qf[u][1] = t1;
        }

        float lrow[2] = {0.f, 0.f};
        f4v o[2][4];
        for (int u = 0; u < 2; ++u)
            for (int t = 0; t < 4; ++t)
                for (int r = 0; r < 4; ++r) o[u][t][r] = 0.f;

        stage(0, 0);
        for (int step = 0; step < nsteps; ++step) {
            const int j0 = step * 64;
            const int cur = step & 1;
            if (step + 1 < nsteps) {
                stage(cur ^ 1, j0 + 64);
                asm volatile("s_waitcnt vmcnt(4)" ::: "memory");  // current tile only
            } else {
                asm volatile("s_waitcnt vmcnt(0)" ::: "memory");
            }
            asm volatile("s_barrier" ::: "memory");

            if (qw + 31 >= j0) {   // wave-uniform; skip fully-masked steps
                f4v st[2][4];
                for (int u = 0; u < 2; ++u)
                    for (int t = 0; t < 4; ++t)
                        for (int r = 0; r < 4; ++r) st[u][t][r] = 0.f;
                __builtin_amdgcn_s_setprio(1);
                for (int t = 0; t < 4; ++t) {
                    int kr = t * 16 + lm;
                    bf8v kf0 = *(const bf8v*)&Kl[cur][kr * 64 + ((lq ^ (kr & 7)) * 8)];
                    bf8v kf1 = *(const bf8v*)&Kl[cur][kr * 64 + (((4 + lq) ^ (kr & 7)) * 8)];
                    for (int u = 0; u < 2; ++u) {
                        st[u][t] = mfma_16x16x32(kf0, qf[u][0], st[u][t]);
                        st[u][t] = mfma_16x16x32(kf1, qf[u][1], st[u][t]);
                    }
                }
                __builtin_amdgcn_s_setprio(0);
                bf8v vf[4][2];
                for (int t = 0; t < 4; ++t) {
                    int vr = t * 16 + lm;
                    vf[t][0] = *(const bf8v*)&Vl[cur][vr * 64 + ((lq ^ (vr & 7)) * 8)];
                    vf[t][1] = *(const bf8v*)&Vl[cur][vr * 64 + (((4 + lq) ^ (vr & 7)) * 8)];
                }
                const bool full = (j0 + 63 <= qw);
                for (int u = 0; u < 2; ++u) {
                    float part = 0.f;
                    if (full) {
                        for (int t = 0; t < 4; ++t)
                            for (int r = 0; r < 4; ++r) {
                                float pv = __builtin_amdgcn_exp2f(st[u][t][r]);
                                st[u][t][r] = pv;
                                part += pv;
                            }
                    } else {
                        const int qi = qw + u * 16 + lm;
                        for (int t = 0; t < 4; ++t)
                            for (int r = 0; r < 4; ++r) {
                                int key = j0 + t * 16 + lq * 4 + r;
                                float pv = (key <= qi)
                                         ? __builtin_amdgcn_exp2f(st[u][t][r]) : 0.f;
                                st[u][t][r] = pv;
                                part += pv;
                            }
                    }
                    lrow[u] += part;
                    for (int t = 0; t < 4; ++t) {
                        union { bf16 h4[4]; uint2 v; } pk;
                        pk.h4[0] = __float2bfloat16(st[u][t][0]);
                        pk.h4[1] = __float2bfloat16(st[u][t][1]);
                        pk.h4[2] = __float2bfloat16(st[u][t][2]);
                        pk.h4[3] = __float2bfloat16(st[u][t][3]);
                        *(uint2*)&pw[wr_addr[t]] = pk.v;
                    }
                    asm volatile("s_waitcnt lgkmcnt(0)" ::: "memory");
                    bf8v pb0 = *(const bf8v*)&pw[rd_addr[0]];
                    bf8v pb1 = *(const bf8v*)&pw[rd_addr[1]];
                    __builtin_amdgcn_s_setprio(1);
                    for (int t = 0; t < 4; ++t) {
                        o[u][t] = mfma_16x16x32(vf[t][0], pb0, o[u][t]);
                        o[u][t] = mfma_16x16x32(vf[t][1], pb1, o[u][t]);
                    }
                    __builtin_amdgcn_s_setprio(0);
                }
            }
            asm volatile("s_barrier" ::: "memory");   // reads done -> next stage may overwrite
        }

        for (int u = 0; u < 2; ++u) {
            lrow[u] += __shfl_xor(lrow[u], 16);
            lrow[u] += __shfl_xor(lrow[u], 32);
            float inv = 1.0f / lrow[u];
            const int qi = qw + u * 16 + lm;
            bf16* orow = O + ((long)(b * cS + qi) * cNH + h) * cDH;
            for (int t = 0; t < 4; ++t) {
                union { bf16 h4[4]; uint2 v; } pk;
                pk.h4[0] = __float2bfloat16(o[u][t][0] * inv);
                pk.h4[1] = __float2bfloat16(o[u][t][1] * inv);
                pk.h4[2] = __float2bfloat16(o[u][t][2] * inv);
                pk.h4[3] = __float2bfloat16(o[u][t][3] * inv);
                *(uint2*)(orow + t * 16 + lq * 4) = pk.v;
            }
        }
    }
}

// ---------------------------------------------------------------------------
// launcher: 4 dispatches
// ---------------------------------------------------------------------------
extern "C" void kernel_launch(void* const* d_in, const int* in_sizes, int n_in,
                              void* d_out, int out_size, void* d_ws, size_t ws_size,
                              hipStream_t stream) {
    const float* hs  = (const float*)d_in[0];
    const int*   pos = (const int*)d_in[1];
    const float* Wq  = (const float*)d_in[2];
    const float* Wk  = (const float*)d_in[3];
    const float* Wv  = (const float*)d_in[4];
    const float* Wo  = (const float*)d_in[5];
    float* out = (float*)d_out;
    char* ws = (char*)d_ws;

    // workspace layout (bytes)
    bf16* hsb = (bf16*)(ws + 0);              // [4096][2048]        16.78 MB
    bf16* WT  = (bf16*)(ws + 16777216);       // [3072][2048] fused QKV^T 12.58 MB
    bf16* WoT = (bf16*)(ws + 29360128);       // [2048][2048]         8.39 MB
    bf16* QKV = (bf16*)(ws + 37748736);       // [4096][3072]        25.17 MB
    bf16* VTb = (bf16*)(ws + 62914560);       // [2][8][64][2048]     4.19 MB
    bf16* AOb = (bf16*)(ws + 67108864);       // [4096][2048]        16.78 MB
    // total 83.9 MB

    // 1) fused prep: hs->bf16 + all weight transposes
    prep_kernel<<<18432, 256, 0, stream>>>(hs, hsb, Wq, Wk, Wv, Wo, WT, WoT);
    // 2) fused QKV projection + K-RoPE + V-transpose epilogue (8-phase 256^2)
    gemm_bt8_qkv<<<dim3(16, 12), 512, 0, stream>>>(hsb, WT, QKV, pos, VTb,
                                                   4096, cQKVW, 2048);
    // 3) attention (R7: 512 uniform blocks, paired q-tiles, XCD affinity)
    attn_kernel<<<512, 256, 0, stream>>>(QKV, VTb, pos, AOb);
    // 4) output projection -> fp32 d_out (8-phase 256^2)
    gemm_bt8<float><<<dim3(16, 8), 512, 0, stream>>>(AOb, WoT, out, 4096, 2048, 2048);
}

// Round 8
// 308.822 us; speedup vs baseline: 1.1127x; 1.0414x over previous
//
#include <hip/hip_runtime.h>
#include <hip/hip_bf16.h>

// ---------------------------------------------------------------------------
// OptimizedAttention R11: 4-dispatch pipeline.
// R10 post-mortem: gemm_bt8_qkv 76us steady (MfmaUtil 26%, VALU 12%, bank
// conflicts 0) on 192/256 CUs; outproj ran on 128/256 CUs (half idle).
// R11:
//   1) outproj -> new 128x256-tile 8-phase kernel, grid 256 = ALL CUs.
//      Ledger: entry {A-u1(t)[1], B(t+1)[4]}=5; vmcnt(6)@ph1, vmcnt(5)@ph3;
//      peels vmcnt(1), vmcnt(0). B consumed in ph0 -> B(t+2) into live buf.
//   2) XCD-chunked block swizzle on both GEMMs (bid%8=XCD; contiguous
//      output-row chunks per XCD -> A-panels L2-resident, less overfetch).
//   3) prep / qkv-fused-epilogue / attn (R7, best measured) frozen.
// B=2 S=2048 H=2048 NH=32 NKV=8 DH=64 N_REP=4 THETA=1e4
// ---------------------------------------------------------------------------

using bf16 = __hip_bfloat16;
typedef __attribute__((ext_vector_type(8))) __bf16 bf8v;   // MFMA A/B frag (4 VGPR)
typedef __attribute__((ext_vector_type(4))) float  f4v;    // MFMA C/D frag

#define AS1 __attribute__((address_space(1)))
#define AS3 __attribute__((address_space(3)))

constexpr int cB = 2, cS = 2048, cH = 2048, cNH = 32, cNKV = 8, cDH = 64;
constexpr int cQKVW = 3072;   // fused QKV row width (2048 Q + 512 K + 512 V)

template <int N> struct ic { static constexpr int value = N; };

__device__ __forceinline__ void async_cp16(const bf16* g, bf16* l) {
    __builtin_amdgcn_global_load_lds((const AS1 unsigned int*)(const void*)g,
                                     (AS3 unsigned int*)(void*)l, 16, 0, 0);
}

__device__ __forceinline__ f4v mfma_16x16x32(bf8v a, bf8v b, f4v c) {
    return __builtin_amdgcn_mfma_f32_16x16x32_bf16(a, b, c, 0, 0, 0);
}

// ---------------------------------------------------------------------------
// prep: fused  hs->bf16 cvt  +  4 weight transposes (f32 [R][C] -> bf16 [C][R])
// ---------------------------------------------------------------------------
__global__ void prep_kernel(const float* __restrict__ hs, bf16* __restrict__ hsb,
                            const float* __restrict__ Wq, const float* __restrict__ Wk,
                            const float* __restrict__ Wv, const float* __restrict__ Wo,
                            bf16* __restrict__ WT, bf16* __restrict__ WoT) {
    __shared__ float tile[32][33];
    const int bz = blockIdx.x, tid = threadIdx.x;
    if (bz < 8192) {
        int i = bz * 256 + tid;
        float4 v = ((const float4*)hs)[i];
        union { bf16 h[4]; uint2 u; } p;
        p.h[0] = __float2bfloat16(v.x);
        p.h[1] = __float2bfloat16(v.y);
        p.h[2] = __float2bfloat16(v.z);
        p.h[3] = __float2bfloat16(v.w);
        ((uint2*)hsb)[i] = p.u;
        return;
    }
    const int t = bz - 8192;
    const float* in; bf16* outp; int C, x, y;
    if (t < 4096)      { in = Wq; outp = WT;               C = 2048; x = t & 63; y = t >> 6; }
    else if (t < 5120) { int l = t - 4096; in = Wk; outp = WT + 2048 * 2048; C = 512; x = l & 15; y = l >> 4; }
    else if (t < 6144) { int l = t - 5120; in = Wv; outp = WT + 2560 * 2048; C = 512; x = l & 15; y = l >> 4; }
    else               { int l = t - 6144; in = Wo; outp = WoT;             C = 2048; x = l & 63; y = l >> 6; }
    const int c0 = x * 32, r0 = y * 32;
    const int tx = tid & 31, ty = tid >> 5;
    for (int i = ty; i < 32; i += 8)
        tile[i][tx] = in[(long)(r0 + i) * C + c0 + tx];
    __syncthreads();
    for (int i = ty; i < 32; i += 8)
        outp[(long)(c0 + i) * 2048 + r0 + tx] = __float2bfloat16(tile[tx][i]);
}

// ---------------------------------------------------------------------------
// 256x256-tile 8-phase GEMM core (R6-verified ledger; see R10 comments).
// BXV/BYV are swizzled block coords.
// ---------------------------------------------------------------------------
#define GEMM_CORE(AARG, BTARG, KARG, BXV, BYV)                                  \
    __shared__ __align__(16) bf16 Al[2][256 * 64];                              \
    __shared__ __align__(16) bf16 Bl[2][256 * 64];                              \
    const int tid  = threadIdx.x;                                               \
    const int lane = tid & 63;                                                  \
    const int wave = tid >> 6;                                                  \
    const int wm = wave >> 2, wn = wave & 3;                                    \
    const int lm = lane & 15, lq = lane >> 4;                                   \
    const int bm = (BXV) * 256, bn = (BYV) * 256;                               \
    const int NT = (KARG) >> 6;                                                 \
    f4v acc[8][4];                                                              \
    _Pragma("unroll")                                                           \
    for (int i = 0; i < 8; ++i)                                                 \
        _Pragma("unroll")                                                       \
        for (int j = 0; j < 4; ++j)                                             \
            for (int r = 0; r < 4; ++r) acc[i][j][r] = 0.f;                     \
    const bf16* aP[2][2]; const bf16* bP[2][2];                                 \
    int aD[2][2], bD[2][2];                                                     \
    _Pragma("unroll")                                                           \
    for (int u = 0; u < 2; ++u)                                                 \
        _Pragma("unroll")                                                       \
        for (int i = 0; i < 2; ++i) {                                           \
            int g = tid + i * 512;                                              \
            int ur = g >> 3, dc = g & 7;                                        \
            int row = ur + (ur & 64) + u * 64;                                  \
            int gch = dc ^ (row & 7);                                           \
            aP[u][i] = (AARG) + (long)(bm + row) * (KARG) + gch * 8;            \
            aD[u][i] = row * 64 + dc * 8;                                       \
        }                                                                       \
    _Pragma("unroll")                                                           \
    for (int h = 0; h < 2; ++h)                                                 \
        _Pragma("unroll")                                                       \
        for (int i = 0; i < 2; ++i) {                                           \
            int g = tid + i * 512;                                              \
            int ur = g >> 3, dc = g & 7;                                        \
            int row = h * 128 + ur;                                             \
            int gch = dc ^ (row & 7);                                           \
            bP[h][i] = (BTARG) + (long)(bn + row) * (KARG) + gch * 8;           \
            bD[h][i] = row * 64 + dc * 8;                                       \
        }                                                                       \
    auto stageA = [&](int buf, int t, int u) {                                  \
        long ko = (long)t * 64;                                                 \
        async_cp16(aP[u][0] + ko, &Al[buf][aD[u][0]]);                          \
        async_cp16(aP[u][1] + ko, &Al[buf][aD[u][1]]);                          \
    };                                                                          \
    auto stageB = [&](int buf, int t, int h) {                                  \
        long ko = (long)t * 64;                                                 \
        async_cp16(bP[h][0] + ko, &Bl[buf][bD[h][0]]);                          \
        async_cp16(bP[h][1] + ko, &Bl[buf][bD[h][1]]);                          \
    };                                                                          \
    const int x7 = lm & 7;                                                      \
    const int co0 = (lq ^ x7) * 8;                                              \
    const int co1 = ((4 + lq) ^ x7) * 8;                                        \
    const int abase = (wm * 128 + lm) * 64;                                     \
    const int bbase = (wn * 64 + lm) * 64;                                      \
    stageB(0, 0, 0); stageB(0, 0, 1); stageA(0, 0, 0); stageA(0, 0, 1);         \
    stageB(1, 1, 0); stageB(1, 1, 1);                                           \
    asm volatile("s_waitcnt vmcnt(6)" ::: "memory");                            \
    asm volatile("s_barrier" ::: "memory");                                     \
    auto ktile = [&](int t, bool ia, bool ib, auto w1, auto w3) {               \
        const int cb = t & 1;                                                   \
        const bf16* Ac = &Al[cb][0];                                            \
        const bf16* Bc = &Bl[cb][0];                                            \
        bf8v bfr[4][2];                                                         \
        _Pragma("unroll")                                                       \
        for (int q = 0; q < 4; ++q) {                                           \
            bf8v afr[2][2];                                                     \
            if (q == 0) {                                                       \
                _Pragma("unroll")                                               \
                for (int n = 0; n < 4; ++n) {                                   \
                    bfr[n][0] = *(const bf8v*)&Bc[bbase + n * 1024 + co0];      \
                    bfr[n][1] = *(const bf8v*)&Bc[bbase + n * 1024 + co1];      \
                }                                                               \
            }                                                                   \
            _Pragma("unroll")                                                   \
            for (int i2 = 0; i2 < 2; ++i2) {                                    \
                afr[i2][0] = *(const bf8v*)&Ac[abase + (q * 2 + i2) * 1024 + co0]; \
                afr[i2][1] = *(const bf8v*)&Ac[abase + (q * 2 + i2) * 1024 + co1]; \
            }                                                                   \
            if (q == 0 && ia) stageA(cb ^ 1, t + 1, 0);                         \
            if (q == 1 && ia) stageA(cb ^ 1, t + 1, 1);                         \
            if (q == 2 && ib) stageB(cb, t + 2, 0);                             \
            if (q == 3 && ib) stageB(cb, t + 2, 1);                             \
            asm volatile("s_barrier" ::: "memory");                             \
            asm volatile("s_waitcnt lgkmcnt(0)" ::: "memory");                  \
            __builtin_amdgcn_s_setprio(1);                                      \
            _Pragma("unroll")                                                   \
            for (int i2 = 0; i2 < 2; ++i2)                                      \
                _Pragma("unroll")                                               \
                for (int n = 0; n < 4; ++n) {                                   \
                    acc[q * 2 + i2][n] = mfma_16x16x32(afr[i2][0], bfr[n][0], acc[q * 2 + i2][n]); \
                    acc[q * 2 + i2][n] = mfma_16x16x32(afr[i2][1], bfr[n][1], acc[q * 2 + i2][n]); \
                }                                                               \
            __builtin_amdgcn_s_setprio(0);                                      \
            if (q == 1) {                                                       \
                if constexpr (decltype(w1)::value == 8)                         \
                    asm volatile("s_waitcnt vmcnt(8)" ::: "memory");            \
                else                                                            \
                    asm volatile("s_waitcnt vmcnt(0)" ::: "memory");            \
            }                                                                   \
            if (q == 3) {                                                       \
                if constexpr (decltype(w3)::value == 1)                         \
                    asm volatile("s_waitcnt vmcnt(6)" ::: "memory");            \
                else if constexpr (decltype(w3)::value == 2)                    \
                    asm volatile("s_waitcnt vmcnt(2)" ::: "memory");            \
            }                                                                   \
            asm volatile("s_barrier" ::: "memory");                             \
        }                                                                       \
    };                                                                          \
    {                                                                           \
        int t = 0;                                                              \
        for (; t + 2 < NT; ++t) ktile(t, true, true, ic<8>{}, ic<1>{});         \
        ktile(t, true, false, ic<8>{}, ic<2>{});                                \
        ++t;                                                                    \
        ktile(t, false, false, ic<0>{}, ic<0>{});                               \
    }

// QKV variant: 1D grid 192, XCD-chunked swizzle (192%8==0 -> bijective):
// xcd = bid&7 owns 24 consecutive lin ids = 2 full M-rows -> 2 A-panels
// (2MB) resident in its L2. byv 0..7 = Q, 8..9 = K (fused RoPE), 10..11 = V
// (transposed store to VT). RoPE pairs (d,d+32) lane-local: acc[mi][n] <->
// acc[mi][n+2].
__global__ __launch_bounds__(512)
void gemm_bt8_qkv(const bf16* __restrict__ A, const bf16* __restrict__ BT,
                  bf16* __restrict__ C, const int* __restrict__ pos,
                  bf16* __restrict__ VTout, int M, int N, int K) {
    const int bid = blockIdx.x;
    const int lin = (bid & 7) * 24 + (bid >> 3);
    const int bxv = lin / 12, byv = lin % 12;
    GEMM_CORE(A, BT, K, bxv, byv)
    if (byv < 8) {
        #pragma unroll
        for (int mi = 0; mi < 8; ++mi) {
            int row = bm + wm * 128 + mi * 16 + lq * 4;
            #pragma unroll
            for (int n = 0; n < 4; ++n) {
                int col = bn + wn * 64 + n * 16 + lm;
                for (int r = 0; r < 4; ++r)
                    C[(long)(row + r) * N + col] = __float2bfloat16(acc[mi][n][r]);
            }
        }
    } else if (byv < 10) {
        #pragma unroll
        for (int mi = 0; mi < 8; ++mi) {
            int row = bm + wm * 128 + mi * 16 + lq * 4;
            float pr[4];
            for (int r = 0; r < 4; ++r) pr[r] = (float)pos[row + r];
            #pragma unroll
            for (int n = 0; n < 2; ++n) {
                int d = n * 16 + lm;
                float inv = __expf(-(float)(2 * d) * (1.0f / 64.0f) * 9.210340371976184f);
                int col = bn + wn * 64 + n * 16 + lm;
                for (int r = 0; r < 4; ++r) {
                    float a  = acc[mi][n][r];
                    float c2 = acc[mi][n + 2][r];
                    float sn, cs;
                    __sincosf(pr[r] * inv, &sn, &cs);
                    C[(long)(row + r) * N + col]      = __float2bfloat16(a * cs - c2 * sn);
                    C[(long)(row + r) * N + col + 32] = __float2bfloat16(c2 * cs + a * sn);
                }
            }
        }
    } else {
        #pragma unroll
        for (int mi = 0; mi < 8; ++mi) {
            int row = bm + wm * 128 + mi * 16 + lq * 4;
            int b = row >> 11, tok = row & 2047;
            #pragma unroll
            for (int n = 0; n < 4; ++n) {
                int vc = bn + wn * 64 + n * 16 + lm - 2560;
                int kv = vc >> 6, d = vc & 63;
                union { bf16 h4[4]; uint2 v; } pk;
                pk.h4[0] = __float2bfloat16(acc[mi][n][0]);
                pk.h4[1] = __float2bfloat16(acc[mi][n][1]);
                pk.h4[2] = __float2bfloat16(acc[mi][n][2]);
                pk.h4[3] = __float2bfloat16(acc[mi][n][3]);
                *(uint2*)&VTout[((long)(b * 8 + kv) * 64 + d) * 2048 + tok] = pk.v;
            }
        }
    }
}

// ---------------------------------------------------------------------------
// 128x256-tile 8-phase GEMM (outproj, f32 out). Grid 256 blocks = all CUs.
// 8 waves (2M x 4N), wave tile 64x64, acc[4][4]; phase q computes M-frag
// mi=q x 4 N-frags x 2k = 8 MFMA; B fully consumed in ph0 (regs) -> B(t+2)
// staged into live buffer's dead B region (2+ barriers after ph0 read).
// A-units interleaved: u = {rows 0..31,64..95} / {32..63,96..127}, 1 load
// per thread each; B halves 2 loads each. In-flight ledger:
//   tile entry: {A-u1(t)[1], B(t+1)[4]} = 5
//   ph0 +A-u0(t+1)=6; ph1 +A-u1(t+1)=7 -> vmcnt(6) lands A-u1(t)
//   ph2 +B-h0(t+2)=8; ph3 +B-h1(t+2)=10 -> vmcnt(5) lands B(t+1)+A-u0(t+1)
// Peels: NT-2 ph3 vmcnt(1); NT-1 ph1 vmcnt(0). Prologue: 10 issues,
// vmcnt(5). LDS 96KB. XCD-chunked swizzle (256%8==0): 32 lin/XCD = 4 full
// M-rows -> 4 A-panels (2MB) L2-resident.
// ---------------------------------------------------------------------------
__global__ __launch_bounds__(512)
void gemm_bt8_128(const bf16* __restrict__ A, const bf16* __restrict__ BT,
                  float* __restrict__ C, int M, int N, int K) {
    __shared__ __align__(16) bf16 Al[2][128 * 64];   // 16 KB x2
    __shared__ __align__(16) bf16 Bl[2][256 * 64];   // 32 KB x2
    const int tid  = threadIdx.x;
    const int lane = tid & 63;
    const int wave = tid >> 6;
    const int wm = wave >> 2, wn = wave & 3;         // 2M x 4N
    const int lm = lane & 15, lq = lane >> 4;
    const int bid = blockIdx.x;
    const int lin = (bid & 7) * 32 + (bid >> 3);
    const int bm = (lin >> 3) * 128, bn = (lin & 7) * 256;
    const int NT = K >> 6;

    f4v acc[4][4];
    #pragma unroll
    for (int i = 0; i < 4; ++i)
        #pragma unroll
        for (int j = 0; j < 4; ++j)
            for (int r = 0; r < 4; ++r) acc[i][j][r] = 0.f;

    // A staging: unit u rows = {0..31,64..95}+32u ; 1 load/thread.
    const bf16* aP[2]; int aD[2];
    #pragma unroll
    for (int u = 0; u < 2; ++u) {
        int ur = tid >> 3, dc = tid & 7;
        int row = (ur & 31) + (ur >> 5) * 64 + u * 32;
        int gch = dc ^ (row & 7);
        aP[u] = A + (long)(bm + row) * K + gch * 8;
        aD[u] = row * 64 + dc * 8;
    }
    // B staging: halves of 128 rows; 2 loads/thread.
    const bf16* bP[2][2]; int bD[2][2];
    #pragma unroll
    for (int h = 0; h < 2; ++h)
        #pragma unroll
        for (int i = 0; i < 2; ++i) {
            int g = tid + i * 512;
            int ur = g >> 3, dc = g & 7;
            int row = h * 128 + ur;
            int gch = dc ^ (row & 7);
            bP[h][i] = BT + (long)(bn + row) * K + gch * 8;
            bD[h][i] = row * 64 + dc * 8;
        }

    auto stageA = [&](int buf, int t, int u) {
        async_cp16(aP[u] + (long)t * 64, &Al[buf][aD[u]]);
    };
    auto stageB = [&](int buf, int t, int h) {
        long ko = (long)t * 64;
        async_cp16(bP[h][0] + ko, &Bl[buf][bD[h][0]]);
        async_cp16(bP[h][1] + ko, &Bl[buf][bD[h][1]]);
    };

    const int x7 = lm & 7;
    const int co0 = (lq ^ x7) * 8;
    const int co1 = ((4 + lq) ^ x7) * 8;
    const int abase = (wm * 64 + lm) * 64;
    const int bbase = (wn * 64 + lm) * 64;

    // prologue: B(0)[4], A-u0(0)[1], A-u1(0)[1], B(1)[4]; keep newest 5
    stageB(0, 0, 0); stageB(0, 0, 1); stageA(0, 0, 0); stageA(0, 0, 1);
    stageB(1, 1, 0); stageB(1, 1, 1);
    asm volatile("s_waitcnt vmcnt(5)" ::: "memory");  // B(0)+A-u0(0) landed
    asm volatile("s_barrier" ::: "memory");

    auto ktile = [&](int t, bool ia, bool ib, auto w1, auto w3) {
        const int cb = t & 1;
        const bf16* Ac = &Al[cb][0];
        const bf16* Bc = &Bl[cb][0];
        bf8v bfr[4][2];
        #pragma unroll
        for (int q = 0; q < 4; ++q) {
            if (q == 0) {
                #pragma unroll
                for (int n = 0; n < 4; ++n) {
                    bfr[n][0] = *(const bf8v*)&Bc[bbase + n * 1024 + co0];
                    bfr[n][1] = *(const bf8v*)&Bc[bbase + n * 1024 + co1];
                }
            }
            bf8v af0 = *(const bf8v*)&Ac[abase + q * 1024 + co0];
            bf8v af1 = *(const bf8v*)&Ac[abase + q * 1024 + co1];
            if (q == 0 && ia) stageA(cb ^ 1, t + 1, 0);
            if (q == 1 && ia) stageA(cb ^ 1, t + 1, 1);
            if (q == 2 && ib) stageB(cb, t + 2, 0);
            if (q == 3 && ib) stageB(cb, t + 2, 1);
            asm volatile("s_barrier" ::: "memory");
            asm volatile("s_waitcnt lgkmcnt(0)" ::: "memory");
            __builtin_amdgcn_s_setprio(1);
            #pragma unroll
            for (int n = 0; n < 4; ++n) {
                acc[q][n] = mfma_16x16x32(af0, bfr[n][0], acc[q][n]);
                acc[q][n] = mfma_16x16x32(af1, bfr[n][1], acc[q][n]);
            }
            __builtin_amdgcn_s_setprio(0);
            if (q == 1) {
                if constexpr (decltype(w1)::value == 6)
                    asm volatile("s_waitcnt vmcnt(6)" ::: "memory");  // A-u1(t) landed
                else
                    asm volatile("s_waitcnt vmcnt(0)" ::: "memory");  // last tile drain
            }
            if (q == 3) {
                if constexpr (decltype(w3)::value == 1)
                    asm volatile("s_waitcnt vmcnt(5)" ::: "memory");  // B(t+1)+A-u0(t+1) landed
                else if constexpr (decltype(w3)::value == 2)
                    asm volatile("s_waitcnt vmcnt(1)" ::: "memory");  // peeled NT-2 boundary
            }
            asm volatile("s_barrier" ::: "memory");
        }
    };

    int t = 0;
    for (; t + 2 < NT; ++t) ktile(t, true, true, ic<6>{}, ic<1>{});
    ktile(t, true, false, ic<6>{}, ic<2>{});   // NT-2: no B(NT) issues
    ++t;
    ktile(t, false, false, ic<0>{}, ic<0>{});  // NT-1: drain A-u1 at ph1

    #pragma unroll
    for (int mi = 0; mi < 4; ++mi) {
        int row = bm + wm * 64 + mi * 16 + lq * 4;
        #pragma unroll
        for (int n = 0; n < 4; ++n) {
            int col = bn + wn * 64 + n * 16 + lm;
            for (int r = 0; r < 4; ++r)
                C[(long)(row + r) * N + col] = acc[mi][n][r];
        }
    }
}

// ---------------------------------------------------------------------------
// Causal GQA flash attention (R7 verbatim -- best measured). 512 blocks;
// paired q-tiles (15-p, p) = uniform 34 steps; 4 waves x 32q; XOR-swizzled
// async K/VT staging, dbuf, s_barrier+vmcnt(4); fixed-base exp2 softmax;
// Q-RoPE fused; setprio around MFMA. XCD affinity: idx&7 = kvh.
// ---------------------------------------------------------------------------
__global__ __launch_bounds__(256)
void attn_kernel(const bf16* __restrict__ QKV, const bf16* __restrict__ VT,
                 const int* __restrict__ pos, bf16* __restrict__ O) {
    __shared__ __align__(16) bf16 Kl[2][64 * 64];   // [buf][key][dh]   8KB x2
    __shared__ __align__(16) bf16 Vl[2][64 * 64];   // [buf][d][key]    8KB x2
    __shared__ __align__(16) bf16 Pl[4][16 * 64];   // per-wave P tile  2KB x4
    const int tid  = threadIdx.x;
    const int wave = tid >> 6, lane = tid & 63;
    const int lm = lane & 15, lq = lane >> 4;
    const int idx = blockIdx.x;
    const int pair = idx >> 6;                      // 0..7
    const int bh2 = idx & 15;
    const int rep = (idx >> 4) & 3;
    const int b = bh2 >> 3, kvh = bh2 & 7;
    const int h = kvh * 4 + rep;

    constexpr float SCALE = 0.18033688011112042f;

    bf16* pw = &Pl[wave][0];
    const int x7 = lm & 7;
    int wr_addr[4], rd_addr[2];
    for (int t = 0; t < 4; ++t)
        wr_addr[t] = lm * 64 + (((t * 2 + (lq >> 1)) ^ x7) * 8) + (lq & 1) * 4;
    for (int c = 0; c < 2; ++c)
        rd_addr[c] = lm * 64 + (((c * 4 + lq) ^ x7) * 8);

    const int srow = tid >> 3, sch = tid & 7;
    const bf16* kgb = QKV + (long)b * cS * cQKVW + 2048 + kvh * cDH;
    const bf16* vgb = VT + (long)(b * cNKV + kvh) * cDH * cS;
    const int sc8 = (sch ^ (srow & 7)) * 8;    // (32+srow)&7 == srow&7
    const bf16* kp0 = kgb + (long)srow * cQKVW + sc8;
    const bf16* kp1 = kgb + (long)(32 + srow) * cQKVW + sc8;
    const bf16* vp0 = vgb + (long)srow * cS + sc8;
    const bf16* vp1 = vgb + (long)(32 + srow) * cS + sc8;
    auto stage = [&](int buf, int j0) {
        long ko = (long)j0 * cQKVW;
        async_cp16(kp0 + ko, &Kl[buf][tid * 8]);
        async_cp16(kp1 + ko, &Kl[buf][2048 + tid * 8]);
        async_cp16(vp0 + j0, &Vl[buf][tid * 8]);
        async_cp16(vp1 + j0, &Vl[buf][2048 + tid * 8]);
    };

    for (int pass = 0; pass < 2; ++pass) {
        const int qblk = pass ? pair : 15 - pair;   // heavy pass first
        const int q0 = qblk * 128;
        const int qw = q0 + wave * 32;              // this wave's 32 queries
        const int nsteps = 2 * qblk + 2;

        bf8v qf[2][2];
        for (int u = 0; u < 2; ++u) {
            const int qi = qw + u * 16 + lm;
            const bf16* qrow = QKV + (long)(b * cS + qi) * cQKVW + h * cDH;
            float p = (float)pos[b * cS + qi];
            bf8v r0 = *(const bf8v*)(qrow + lq * 8);
            bf8v r1 = *(const bf8v*)(qrow + 32 + lq * 8);
            bf8v t0, t1;
            for (int j = 0; j < 8; ++j) {
                int d = lq * 8 + j;
                float inv = __expf(-(float)(2 * d) * (1.0f / 64.0f) * 9.210340371976184f);
                float sn, cs;
                __sincosf(p * inv, &sn, &cs);
                float a = (float)r0[j], c2 = (float)r1[j];
                t0[j] = (__bf16)((a * cs - c2 * sn) * SCALE);
                t1[j] = (__bf16)((c2 * cs + a * sn) * SCALE);
            }
            qf[u][0] = t0; qf[u][1] = t1;
        }

        float lrow[2] = {0.f, 0.f};
        f4v o[2][4];
        for (int u = 0; u < 2; ++u)
            for (int t = 0; t < 4; ++t)
                for (int r = 0; r < 4; ++r) o[u][t][r] = 0.f;

        stage(0, 0);
        for (int step = 0; step < nsteps; ++step) {
            const int j0 = step * 64;
            const int cur = step & 1;
            if (step + 1 < nsteps) {
                stage(cur ^ 1, j0 + 64);
                asm volatile("s_waitcnt vmcnt(4)" ::: "memory");  // current tile only
            } else {
                asm volatile("s_waitcnt vmcnt(0)" ::: "memory");
            }
            asm volatile("s_barrier" ::: "memory");

            if (qw + 31 >= j0) {   // wave-uniform; skip fully-masked steps
                f4v st[2][4];
                for (int u = 0; u < 2; ++u)
                    for (int t = 0; t < 4; ++t)
                        for (int r = 0; r < 4; ++r) st[u][t][r] = 0.f;
                __builtin_amdgcn_s_setprio(1);
                for (int t = 0; t < 4; ++t) {
                    int kr = t * 16 + lm;
                    bf8v kf0 = *(const bf8v*)&Kl[cur][kr * 64 + ((lq ^ (kr & 7)) * 8)];
                    bf8v kf1 = *(const bf8v*)&Kl[cur][kr * 64 + (((4 + lq) ^ (kr & 7)) * 8)];
                    for (int u = 0; u < 2; ++u) {
                        st[u][t] = mfma_16x16x32(kf0, qf[u][0], st[u][t]);
                        st[u][t] = mfma_16x16x32(kf1, qf[u][1], st[u][t]);
                    }
                }
                __builtin_amdgcn_s_setprio(0);
                bf8v vf[4][2];
                for (int t = 0; t < 4; ++t) {
                    int vr = t * 16 + lm;
                    vf[t][0] = *(const bf8v*)&Vl[cur][vr * 64 + ((lq ^ (vr & 7)) * 8)];
                    vf[t][1] = *(const bf8v*)&Vl[cur][vr * 64 + (((4 + lq) ^ (vr & 7)) * 8)];
                }
                const bool full = (j0 + 63 <= qw);
                for (int u = 0; u < 2; ++u) {
                    float part = 0.f;
                    if (full) {
                        for (int t = 0; t < 4; ++t)
                            for (int r = 0; r < 4; ++r) {
                                float pv = __builtin_amdgcn_exp2f(st[u][t][r]);
                                st[u][t][r] = pv;
                                part += pv;
                            }
                    } else {
                        const int qi = qw + u * 16 + lm;
                        for (int t = 0; t < 4; ++t)
                            for (int r = 0; r < 4; ++r) {
                                int key = j0 + t * 16 + lq * 4 + r;
                                float pv = (key <= qi)
                                         ? __builtin_amdgcn_exp2f(st[u][t][r]) : 0.f;
                                st[u][t][r] = pv;
                                part += pv;
                            }
                    }
                    lrow[u] += part;
                    for (int t = 0; t < 4; ++t) {
                        union { bf16 h4[4]; uint2 v; } pk;
                        pk.h4[0] = __float2bfloat16(st[u][t][0]);
                        pk.h4[1] = __float2bfloat16(st[u][t][1]);
                        pk.h4[2] = __float2bfloat16(st[u][t][2]);
                        pk.h4[3] = __float2bfloat16(st[u][t][3]);
                        *(uint2*)&pw[wr_addr[t]] = pk.v;
                    }
                    asm volatile("s_waitcnt lgkmcnt(0)" ::: "memory");
                    bf8v pb0 = *(const bf8v*)&pw[rd_addr[0]];
                    bf8v pb1 = *(const bf8v*)&pw[rd_addr[1]];
                    __builtin_amdgcn_s_setprio(1);
                    for (int t = 0; t < 4; ++t) {
                        o[u][t] = mfma_16x16x32(vf[t][0], pb0, o[u][t]);
                        o[u][t] = mfma_16x16x32(vf[t][1], pb1, o[u][t]);
                    }
                    __builtin_amdgcn_s_setprio(0);
                }
            }
            asm volatile("s_barrier" ::: "memory");   // reads done -> next stage may overwrite
        }

        for (int u = 0; u < 2; ++u) {
            lrow[u] += __shfl_xor(lrow[u], 16);
            lrow[u] += __shfl_xor(lrow[u], 32);
            float inv = 1.0f / lrow[u];
            const int qi = qw + u * 16 + lm;
            bf16* orow = O + ((long)(b * cS + qi) * cNH + h) * cDH;
            for (int t = 0; t < 4; ++t) {
                union { bf16 h4[4]; uint2 v; } pk;
                pk.h4[0] = __float2bfloat16(o[u][t][0] * inv);
                pk.h4[1] = __float2bfloat16(o[u][t][1] * inv);
                pk.h4[2] = __float2bfloat16(o[u][t][2] * inv);
                pk.h4[3] = __float2bfloat16(o[u][t][3] * inv);
                *(uint2*)(orow + t * 16 + lq * 4) = pk.v;
            }
        }
    }
}

// ---------------------------------------------------------------------------
// launcher: 4 dispatches
// ---------------------------------------------------------------------------
extern "C" void kernel_launch(void* const* d_in, const int* in_sizes, int n_in,
                              void* d_out, int out_size, void* d_ws, size_t ws_size,
                              hipStream_t stream) {
    const float* hs  = (const float*)d_in[0];
    const int*   pos = (const int*)d_in[1];
    const float* Wq  = (const float*)d_in[2];
    const float* Wk  = (const float*)d_in[3];
    const float* Wv  = (const float*)d_in[4];
    const float* Wo  = (const float*)d_in[5];
    float* out = (float*)d_out;
    char* ws = (char*)d_ws;

    // workspace layout (bytes)
    bf16* hsb = (bf16*)(ws + 0);              // [4096][2048]        16.78 MB
    bf16* WT  = (bf16*)(ws + 16777216);       // [3072][2048] fused QKV^T 12.58 MB
    bf16* WoT = (bf16*)(ws + 29360128);       // [2048][2048]         8.39 MB
    bf16* QKV = (bf16*)(ws + 37748736);       // [4096][3072]        25.17 MB
    bf16* VTb = (bf16*)(ws + 62914560);       // [2][8][64][2048]     4.19 MB
    bf16* AOb = (bf16*)(ws + 67108864);       // [4096][2048]        16.78 MB
    // total 83.9 MB

    // 1) fused prep: hs->bf16 + all weight transposes
    prep_kernel<<<18432, 256, 0, stream>>>(hs, hsb, Wq, Wk, Wv, Wo, WT, WoT);
    // 2) fused QKV projection + K-RoPE + V-transpose (8-phase 256^2, XCD swz)
    gemm_bt8_qkv<<<192, 512, 0, stream>>>(hsb, WT, QKV, pos, VTb,
                                          4096, cQKVW, 2048);
    // 3) attention (R7: 512 uniform blocks, paired q-tiles, XCD affinity)
    attn_kernel<<<512, 256, 0, stream>>>(QKV, VTb, pos, AOb);
    // 4) output projection -> fp32 d_out (8-phase 128x256, 256 blocks, XCD swz)
    gemm_bt8_128<<<256, 512, 0, stream>>>(AOb, WoT, out, 4096, 2048, 2048);
}